// Round 7
// baseline (580.493 us; speedup 1.0000x reference)
//
#include <hip/hip_runtime.h>
#include <math.h>

#define B_   192
#define C_   512
#define HW_  784
#define TPK  23          // int(784*0.03)
#define PPAD 896         // 7 p-tiles of 128

typedef __attribute__((ext_vector_type(8))) short s8bf;
typedef __attribute__((ext_vector_type(4))) float f4;
typedef __attribute__((ext_vector_type(8))) unsigned short us8;

__device__ __forceinline__ float sigf(float x) {
    return 1.0f / (1.0f + __expf(-x));
}
__device__ __forceinline__ unsigned short f2bf(float f) {
    unsigned u = __float_as_uint(f);
    unsigned r = u + 0x7FFFu + ((u >> 16) & 1u);
    return (unsigned short)(r >> 16);
}
__device__ __forceinline__ float bf2f(unsigned short u) {
    return __uint_as_float(((unsigned)u) << 16);
}
__device__ __forceinline__ void gld16(const unsigned short* g, unsigned short* l) {
    __builtin_amdgcn_global_load_lds((const __attribute__((address_space(1))) unsigned int*)g,
                                     (__attribute__((address_space(3))) unsigned int*)l, 16, 0, 0);
}

// ---------------------------------------------------------------- evmean (fallback only)
__global__ void k_evmean(const float* __restrict__ ev, float* __restrict__ evmean) {
    int row  = blockIdx.x * 4 + (threadIdx.x >> 6);
    int lane = threadIdx.x & 63;
    const float4* s4 = (const float4*)(ev + (size_t)row * HW_);
    float s = 0.f;
    for (int i = lane; i < HW_ / 4; i += 64) {
        float4 v = s4[i];
        s += v.x + v.y + v.z + v.w;
    }
    for (int off = 32; off > 0; off >>= 1) s += __shfl_down(s, off, 64);
    if (lane == 0) evmean[row] = s * (1.0f / HW_);
}

// ---------------------------------------------------------------- tiled fp32 GEMM w/ split-K
template<int BKN, int RELUA, int BF16OUT, int SPLITK>
__global__ __launch_bounds__(256)
void k32(const float* __restrict__ A, const float* __restrict__ B,
         void* __restrict__ Cv, int M, int N, int K) {
    __shared__ float As[16][68];
    __shared__ float Bs[16][68];
    int m0 = blockIdx.y * 64, n0 = blockIdx.x * 64;
    int kslice = K / SPLITK;
    int kbeg = blockIdx.z * kslice;
    int tid = threadIdx.x;
    int tx = tid & 15, ty = tid >> 4;
    int r = tid >> 2, c4 = tid & 3;

    float acc[4][4];
#pragma unroll
    for (int i = 0; i < 4; i++)
#pragma unroll
        for (int j = 0; j < 4; j++) acc[i][j] = 0.f;

    for (int k0 = kbeg; k0 < kbeg + kslice; k0 += 16) {
        float4 av = *(const float4*)(A + (size_t)(m0 + r) * K + k0 + c4 * 4);
        if (RELUA) {
            av.x = fmaxf(av.x, 0.f); av.y = fmaxf(av.y, 0.f);
            av.z = fmaxf(av.z, 0.f); av.w = fmaxf(av.w, 0.f);
        }
        As[c4 * 4 + 0][r] = av.x; As[c4 * 4 + 1][r] = av.y;
        As[c4 * 4 + 2][r] = av.z; As[c4 * 4 + 3][r] = av.w;
        if (BKN == 0) {
            float4 bv = *(const float4*)(B + (size_t)(n0 + r) * K + k0 + c4 * 4);
            Bs[c4 * 4 + 0][r] = bv.x; Bs[c4 * 4 + 1][r] = bv.y;
            Bs[c4 * 4 + 2][r] = bv.z; Bs[c4 * 4 + 3][r] = bv.w;
        } else {
            float4 bv = *(const float4*)(B + (size_t)(k0 + ty) * N + n0 + tx * 4);
            Bs[ty][tx * 4 + 0] = bv.x; Bs[ty][tx * 4 + 1] = bv.y;
            Bs[ty][tx * 4 + 2] = bv.z; Bs[ty][tx * 4 + 3] = bv.w;
        }
        __syncthreads();
#pragma unroll
        for (int kk = 0; kk < 16; kk++) {
            float a_[4];
#pragma unroll
            for (int i = 0; i < 4; i++) a_[i] = As[kk][ty * 4 + i];
            float4 bb = *(const float4*)&Bs[kk][tx * 4];
#pragma unroll
            for (int i = 0; i < 4; i++) {
                acc[i][0] = fmaf(a_[i], bb.x, acc[i][0]);
                acc[i][1] = fmaf(a_[i], bb.y, acc[i][1]);
                acc[i][2] = fmaf(a_[i], bb.z, acc[i][2]);
                acc[i][3] = fmaf(a_[i], bb.w, acc[i][3]);
            }
        }
        __syncthreads();
    }
#pragma unroll
    for (int i = 0; i < 4; i++) {
        if (SPLITK > 1) {
            float* C = (float*)Cv;
            float* row = C + (size_t)(m0 + ty * 4 + i) * N + n0 + tx * 4;
#pragma unroll
            for (int j = 0; j < 4; j++) atomicAdd(&row[j], acc[i][j]);
        } else if (BF16OUT) {
            unsigned short* C16 = (unsigned short*)Cv;
            ushort4 o;
            o.x = f2bf(acc[i][0]); o.y = f2bf(acc[i][1]);
            o.z = f2bf(acc[i][2]); o.w = f2bf(acc[i][3]);
            *(ushort4*)(C16 + (size_t)(m0 + ty * 4 + i) * N + n0 + tx * 4) = o;
        } else {
            float* C = (float*)Cv;
            *(float4*)(C + (size_t)(m0 + ty * 4 + i) * N + n0 + tx * 4) =
                make_float4(acc[i][0], acc[i][1], acc[i][2], acc[i][3]);
        }
    }
}

// ---------------------------------------------------------------- iv_norm = l2norm(ind_vec) per row
__global__ void k_rownorm(const float* __restrict__ iv, float* __restrict__ ivn) {
    int b = blockIdx.x, lane = threadIdx.x;
    float v[8]; float s = 0.f;
#pragma unroll
    for (int k = 0; k < 8; k++) {
        v[k] = iv[(size_t)b * C_ + lane + 64 * k];
        s = fmaf(v[k], v[k], s);
    }
#pragma unroll
    for (int off = 32; off > 0; off >>= 1) s += __shfl_xor(s, off, 64);
    float rn = 1.0f / fmaxf(sqrtf(s), 1e-12f);
#pragma unroll
    for (int k = 0; k < 8; k++) ivn[(size_t)b * C_ + lane + 64 * k] = v[k] * rn;
}

// ---------------------------------------------------------------- Abf rows 0..511 = bf16(Wv), rows 704..767 = 0
__global__ void k_prepA(const float* __restrict__ Wv, unsigned short* __restrict__ Abf) {
    int r = blockIdx.x, tid = threadIdx.x;
    int row = (r < 512) ? r : (192 + r);   // 512..575 -> 704..767 zero pad
    for (int i = 0; i < 2; i++) {
        int c = tid + i * 256;
        float v = (r < 512) ? Wv[(size_t)r * C_ + c] : 0.f;
        Abf[(size_t)row * C_ + c] = f2bf(v);
    }
}

// ---------------------------------------------------------------- ev[b][c][p] fp32 -> evT[bl][p][c] bf16 (64x64 tiles)
__global__ __launch_bounds__(256)
void k_transpose64(const float* __restrict__ ev, unsigned short* __restrict__ evT,
                   float* __restrict__ evsum, int doevm, int b0) {
    __shared__ float t[64][67];
    int bl = blockIdx.z, b = b0 + bl;
    int c0 = blockIdx.y * 64, p0 = blockIdx.x * 64;
    int tid = threadIdx.x;
    int cl = tid >> 4;
    int pc = tid & 15;
    int p = p0 + pc * 4;
#pragma unroll
    for (int q = 0; q < 4; q++) {
        int c_local = q * 16 + cl;
        const float* src = ev + ((size_t)b * C_ + c0 + c_local) * HW_;
        float4 v = make_float4(0.f, 0.f, 0.f, 0.f);
        if (p + 3 < HW_) v = *(const float4*)(src + p);
        else if (p < HW_) { for (int j = 0; j < 4; j++) if (p + j < HW_) ((float*)&v)[j] = src[p + j]; }
        if (doevm) {
            float rs = v.x + v.y + v.z + v.w;
            rs += __shfl_xor(rs, 1, 16);
            rs += __shfl_xor(rs, 2, 16);
            rs += __shfl_xor(rs, 4, 16);
            rs += __shfl_xor(rs, 8, 16);
            if (pc == 0) atomicAdd(&evsum[b * C_ + c0 + c_local], rs * (1.0f / HW_));
        }
        t[c_local][pc * 4 + 0] = v.x; t[c_local][pc * 4 + 1] = v.y;
        t[c_local][pc * 4 + 2] = v.z; t[c_local][pc * 4 + 3] = v.w;
    }
    __syncthreads();
    int r = tid >> 3;
    int j = tid & 7;
#pragma unroll
    for (int q = 0; q < 2; q++) {
        int row = r + q * 32;
        us8 o;
#pragma unroll
        for (int k = 0; k < 8; k++) o[k] = f2bf(t[j * 8 + k][row]);
        *(us8*)(evT + ((size_t)bl * PPAD + p0 + row) * C_ + c0 + j * 8) = o;
    }
}

// ---------------------------------------------------------------- MFMA GEMM: [Wv;U](704x512) @ ev[b](512x784)
__global__ __launch_bounds__(256, 4)
void k_gemm(const unsigned short* __restrict__ Abf, const unsigned short* __restrict__ evT,
            float* __restrict__ n2, unsigned short* __restrict__ Tb, int b0, int nb) {
    __shared__ unsigned short As[2][4096];   // [128][32]
    __shared__ unsigned short Bs[2][4096];   // [128][32]

    int id = blockIdx.x;
    int xcd = id & 7, slot = id >> 3;
    int S = (nb * 42 + 7) >> 3;
    int w = xcd * S + slot;
    if (w >= nb * 42) return;
    int bl = w / 42, rem = w % 42;
    int pt = rem / 6, ot = rem % 6;
    int o0 = ot * 128, p0 = pt * 128;

    int tid = threadIdx.x;
    int wid = tid >> 6, lane = tid & 63;
    int wy = wid >> 1, wx = wid & 1;
    int l15 = lane & 15, l4 = lane >> 4;

    const unsigned short* Ag = Abf + ((size_t)o0 + (tid >> 2)) * C_ + (tid & 3) * 8;
    const unsigned short* Bg = evT + ((size_t)(b0 + bl) * PPAD + p0 + (tid >> 2)) * C_ + (tid & 3) * 8;
    int lds_off = wid * 512 + lane * 8;

    f4 acc[4][4] = {};
    int cur = 0;

#define STAGE(buf, k0) do { \
    gld16(Ag + (k0),             &As[buf][0] + lds_off); \
    gld16(Ag + (k0) + 64 * C_,   &As[buf][2048] + lds_off); \
    gld16(Bg + (k0),             &Bs[buf][0] + lds_off); \
    gld16(Bg + (k0) + 64 * C_,   &Bs[buf][2048] + lds_off); \
} while (0)

    STAGE(0, 0);
    __syncthreads();
    for (int t = 0; t < 16; ++t) {
        if (t < 15) STAGE(cur ^ 1, (t + 1) * 32);
        const s8bf* Ar = (const s8bf*)&As[cur][0];
        const s8bf* Br = (const s8bf*)&Bs[cur][0];
        s8bf a[4], b[4];
#pragma unroll
        for (int mi = 0; mi < 4; mi++) a[mi] = Ar[(wy * 64 + mi * 16 + l15) * 4 + l4];
#pragma unroll
        for (int ni = 0; ni < 4; ni++) b[ni] = Br[(wx * 64 + ni * 16 + l15) * 4 + l4];
#pragma unroll
        for (int mi = 0; mi < 4; mi++)
#pragma unroll
            for (int ni = 0; ni < 4; ni++)
                acc[mi][ni] = __builtin_amdgcn_mfma_f32_16x16x32_bf16(a[mi], b[ni], acc[mi][ni], 0, 0, 0);
        __syncthreads();
        cur ^= 1;
    }
#undef STAGE

    if (ot < 4) {
        float* red = (float*)&As[0][0];
#pragma unroll
        for (int ni = 0; ni < 4; ni++) {
            float s = 0.f;
#pragma unroll
            for (int mi = 0; mi < 4; mi++)
#pragma unroll
                for (int r = 0; r < 4; r++) { float x = acc[mi][ni][r]; s = fmaf(x, x, s); }
            red[(wy * 4 + l4) * 128 + wx * 64 + ni * 16 + l15] = s;
        }
        __syncthreads();
        if (tid < 128) {
            float s = 0.f;
#pragma unroll
            for (int q = 0; q < 8; q++) s += red[q * 128 + tid];
            int p = p0 + tid;
            if (p < HW_) atomicAdd(&n2[(size_t)(b0 + bl) * HW_ + p], s);
        }
    } else {
        int dbase = o0 - 512 + wy * 64;
#pragma unroll
        for (int mi = 0; mi < 4; mi++)
#pragma unroll
            for (int r = 0; r < 4; r++) {
                int dd = dbase + mi * 16 + l4 * 4 + r;
                if (dd < B_) {
                    size_t rowoff = ((size_t)(b0 + bl) * B_ + dd) * HW_;
#pragma unroll
                    for (int ni = 0; ni < 4; ni++) {
                        int p = p0 + wx * 64 + ni * 16 + l15;
                        if (p < HW_) Tb[rowoff + p] = f2bf(acc[mi][ni][r]);
                    }
                }
            }
    }
}

// ---------------------------------------------------------------- invn[b,p] = 1/max(sqrt(n2),1e-12)
__global__ void k_invn(const float* __restrict__ n2, float* __restrict__ invn, int n) {
    int i = blockIdx.x * 256 + threadIdx.x;
    if (i >= n) return;
    invn[i] = 1.0f / fmaxf(sqrtf(n2[i]), 1e-12f);
}

// ---------------------------------------------------------------- pool: wave per (b,d); dual interleaved bisection
__global__ __launch_bounds__(256)
void k_pool(const unsigned short* __restrict__ T, const float* __restrict__ invn,
            float* __restrict__ SP, float* __restrict__ SN, int b0) {
    int tid = threadIdx.x;
    int wv = tid >> 6, lane = tid & 63;
    int d = blockIdx.x * 4 + wv;
    int bl = blockIdx.y, b = b0 + bl;
    const unsigned short* Trow = T + ((size_t)b * B_ + d) * HW_;
    const float* nrow = invn + (size_t)b * HW_;
    float sv[13];
#pragma unroll
    for (int i = 0; i < 12; i++) {
        int p = lane + i * 64;
        sv[i] = bf2f(Trow[p]) * nrow[p];
    }
    {
        int p = lane + 768;
        sv[12] = (p < HW_) ? bf2f(Trow[p]) * nrow[p] : __uint_as_float(0x7FC00000u);
    }
    float vmax = -1e30f, vmin = 1e30f;
#pragma unroll
    for (int i = 0; i < 13; i++) { vmax = fmaxf(vmax, sv[i]); vmin = fminf(vmin, sv[i]); }
#pragma unroll
    for (int off = 32; off > 0; off >>= 1) {
        vmax = fmaxf(vmax, __shfl_xor(vmax, off, 64));
        vmin = fminf(vmin, __shfl_xor(vmin, off, 64));
    }
    float lo1 = vmin, hi1 = vmax, lo2 = vmin, hi2 = vmax;
    for (int it = 0; it < 13; ++it) {
        float m1 = 0.5f * (lo1 + hi1), m2 = 0.5f * (lo2 + hi2);
        int c1 = 0, c2 = 0;
#pragma unroll
        for (int i = 0; i < 13; i++) {
            c1 += __popcll(__ballot(sv[i] >= m1));
            c2 += __popcll(__ballot(sv[i] <= m2));
        }
        if (c1 >= TPK) lo1 = m1; else hi1 = m1;
        if (c2 >= TPK) hi2 = m2; else lo2 = m2;
    }
    float thrp = lo1, thrn = hi2;
    const float its = 1.0f / 0.03f;
    float spn = 0.f, spd = 0.f, snn = 0.f, snd = 0.f;
#pragma unroll
    for (int i = 0; i < 13; i++) {
        if (i == 12 && lane >= 16) continue;
        float s = sv[i];
        float mp = sigf((s - thrp) * its);
        float mn = sigf(-(s - thrn) * its);
        spn += s * mp; spd += mp;
        snn += s * mn; snd += mn;
    }
    for (int off = 32; off > 0; off >>= 1) {
        spn += __shfl_down(spn, off, 64);
        spd += __shfl_down(spd, off, 64);
        snn += __shfl_down(snn, off, 64);
        snd += __shfl_down(snd, off, 64);
    }
    if (lane == 0) {
        SP[b * B_ + d] = spn / spd;
        SN[b * B_ + d] = snn / snd;
    }
}

// ---------------------------------------------------------------- CE losses
__global__ void k_loss12(const float* __restrict__ SP, const float* __restrict__ SN,
                         float* __restrict__ acc) {
    __shared__ float red[128];
    int i = blockIdx.x, tid = threadIdx.x;
    const float itc = 1.0f / 0.07f;
    for (int phase = 0; phase < 2; phase++) {
        float mx = -INFINITY;
        for (int j = tid; j < 2 * B_; j += 128) {
            float v;
            if (phase == 0) v = (j < B_ ? SP[i * B_ + j] : SN[i * B_ + (j - B_)]);
            else            v = (j < B_ ? SP[j * B_ + i] : SN[(j - B_) * B_ + i]);
            mx = fmaxf(mx, v * itc);
        }
        red[tid] = mx; __syncthreads();
        for (int s = 64; s > 0; s >>= 1) { if (tid < s) red[tid] = fmaxf(red[tid], red[tid + s]); __syncthreads(); }
        mx = red[0]; __syncthreads();
        float se = 0.f;
        for (int j = tid; j < 2 * B_; j += 128) {
            float v;
            if (phase == 0) v = (j < B_ ? SP[i * B_ + j] : SN[i * B_ + (j - B_)]);
            else            v = (j < B_ ? SP[j * B_ + i] : SN[(j - B_) * B_ + i]);
            se += __expf(v * itc - mx);
        }
        red[tid] = se; __syncthreads();
        for (int s = 64; s > 0; s >>= 1) { if (tid < s) red[tid] += red[tid + s]; __syncthreads(); }
        if (tid == 0) {
            float lse = logf(red[0]) + mx;
            atomicAdd(&acc[phase], lse - SP[i * B_ + i] * itc);
        }
        __syncthreads();
    }
}

// ---------------------------------------------------------------- fused distance matrix + final (last block)
__global__ __launch_bounds__(256)
void k_distfin(const float* __restrict__ iv, const float* __restrict__ ivn,
               const float* __restrict__ fa, const float* __restrict__ acc,
               float* __restrict__ rowsum, float* __restrict__ colsum,
               int* __restrict__ cnt, float* __restrict__ out) {
    __shared__ float Ai[16][68], An[16][68], Bf[16][68], Bn[16][68];
    __shared__ float rred[64][17], cred[64][17];
    __shared__ float fr[256];
    __shared__ int lastf;
    int i0 = blockIdx.y * 64, j0 = blockIdx.x * 64;
    int tid = threadIdx.x;
    int tx = tid & 15, ty = tid >> 4;
    int r = tid >> 2, c4 = tid & 3;
    float accD[4][4], accV[4][4];
#pragma unroll
    for (int i = 0; i < 4; i++)
#pragma unroll
        for (int j = 0; j < 4; j++) { accD[i][j] = 0.f; accV[i][j] = 0.f; }

    for (int k0 = 0; k0 < C_; k0 += 16) {
        float4 v;
        v = *(const float4*)(iv + (size_t)(i0 + r) * C_ + k0 + c4 * 4);
        Ai[c4*4+0][r]=v.x; Ai[c4*4+1][r]=v.y; Ai[c4*4+2][r]=v.z; Ai[c4*4+3][r]=v.w;
        v = *(const float4*)(ivn + (size_t)(i0 + r) * C_ + k0 + c4 * 4);
        An[c4*4+0][r]=v.x; An[c4*4+1][r]=v.y; An[c4*4+2][r]=v.z; An[c4*4+3][r]=v.w;
        v = *(const float4*)(fa + (size_t)(j0 + r) * C_ + k0 + c4 * 4);
        Bf[c4*4+0][r]=v.x; Bf[c4*4+1][r]=v.y; Bf[c4*4+2][r]=v.z; Bf[c4*4+3][r]=v.w;
        v = *(const float4*)(ivn + (size_t)(j0 + r) * C_ + k0 + c4 * 4);
        Bn[c4*4+0][r]=v.x; Bn[c4*4+1][r]=v.y; Bn[c4*4+2][r]=v.z; Bn[c4*4+3][r]=v.w;
        __syncthreads();
#pragma unroll
        for (int kk = 0; kk < 16; kk++) {
            float ai[4], an[4];
#pragma unroll
            for (int i = 0; i < 4; i++) { ai[i] = Ai[kk][ty*4+i]; an[i] = An[kk][ty*4+i]; }
            float4 bf = *(const float4*)&Bf[kk][tx*4];
            float4 bn = *(const float4*)&Bn[kk][tx*4];
#pragma unroll
            for (int i = 0; i < 4; i++) {
                float d0 = ai[i] - bf.x + 1e-6f; accD[i][0] = fmaf(d0, d0, accD[i][0]);
                float d1 = ai[i] - bf.y + 1e-6f; accD[i][1] = fmaf(d1, d1, accD[i][1]);
                float d2 = ai[i] - bf.z + 1e-6f; accD[i][2] = fmaf(d2, d2, accD[i][2]);
                float d3 = ai[i] - bf.w + 1e-6f; accD[i][3] = fmaf(d3, d3, accD[i][3]);
                accV[i][0] = fmaf(an[i], bn.x, accV[i][0]);
                accV[i][1] = fmaf(an[i], bn.y, accV[i][1]);
                accV[i][2] = fmaf(an[i], bn.z, accV[i][2]);
                accV[i][3] = fmaf(an[i], bn.w, accV[i][3]);
            }
        }
        __syncthreads();
    }
    float rp[4] = {0.f, 0.f, 0.f, 0.f};
    float cp[4] = {0.f, 0.f, 0.f, 0.f};
#pragma unroll
    for (int i = 0; i < 4; i++)
#pragma unroll
        for (int j = 0; j < 4; j++) {
            int gi = i0 + ty * 4 + i, gj = j0 + tx * 4 + j;
            float val = (gi == gj) ? accD[i][j] : accD[i][j] * accV[i][j] * (1.0f / 191.0f);
            rp[i] += val; cp[j] += val;
        }
#pragma unroll
    for (int i = 0; i < 4; i++) rred[ty * 4 + i][tx] = rp[i];
#pragma unroll
    for (int j = 0; j < 4; j++) cred[tx * 4 + j][ty] = cp[j];
    __syncthreads();
    if (tid < 64) {
        float s = 0.f;
#pragma unroll
        for (int q = 0; q < 16; q++) s += rred[tid][q];
        atomicAdd(&rowsum[i0 + tid], s);
    } else if (tid < 128) {
        int t = tid - 64;
        float s = 0.f;
#pragma unroll
        for (int q = 0; q < 16; q++) s += cred[t][q];
        atomicAdd(&colsum[j0 + t], s);
    }
    __threadfence();
    __syncthreads();
    if (tid == 0) lastf = (atomicAdd(cnt, 1) == 8);
    __syncthreads();
    if (lastf) {
        __threadfence();
        float v3 = (tid < B_) ? fmaxf(rowsum[tid] + 0.6f, 0.f) : 0.f;
        float v4 = (tid < B_) ? fmaxf(colsum[tid] + 0.6f, 0.f) : 0.f;
        fr[tid] = v3; __syncthreads();
        for (int s = 128; s > 0; s >>= 1) { if (tid < s) fr[tid] += fr[tid + s]; __syncthreads(); }
        float l3 = fr[0] / B_;
        __syncthreads();
        fr[tid] = v4; __syncthreads();
        for (int s = 128; s > 0; s >>= 1) { if (tid < s) fr[tid] += fr[tid + s]; __syncthreads(); }
        float l4 = fr[0] / B_;
        if (tid == 0) {
            out[0] = 0.5f * (acc[0] + acc[1]) / B_;
            out[1] = 0.5f * (l3 + l4);
        }
    }
}

extern "C" void kernel_launch(void* const* d_in, const int* in_sizes, int n_in,
                              void* d_out, int out_size, void* d_ws, size_t ws_size,
                              hipStream_t stream) {
    const float* ev  = (const float*)d_in[0];
    const float* ea  = (const float*)d_in[1];
    const float* Wv  = (const float*)d_in[2];
    const float* Wa1 = (const float*)d_in[3];
    const float* Wa2 = (const float*)d_in[4];
    float* out = (float*)d_out;
    float* ws  = (float*)d_ws;

    size_t off = 0;
    // one contiguous zero block: evmean..fa, n2, acc/rowsum/colsum/cnt
    float* evmean  = ws + off; off += B_ * C_;
    float* ind_vec = ws + off; off += B_ * C_;
    float* Hb      = ws + off; off += B_ * C_;
    float* fa      = ws + off; off += B_ * C_;
    float* n2      = ws + off; off += B_ * HW_;
    float* accb    = ws + off;
    float* rowsum  = accb + 16;
    float* colsum  = rowsum + B_;
    int*   cntp    = (int*)(colsum + B_);
    off += 16 + B_ + B_ + 16;
    size_t zero_count = off;   // everything from ws[0]..ws[off) zeroed in one shot
    float* iv_norm = ws + off; off += B_ * C_;
    float* invn    = ws + off; off += B_ * HW_;
    float* SPb     = ws + off; off += B_ * B_;
    float* SNb     = ws + off; off += B_ * B_;
    unsigned short* Abf = (unsigned short*)(ws + off); off += 768 * C_ / 2;

    size_t perB_f = (size_t)PPAD * C_ / 2 + (size_t)B_ * HW_ / 2;
    size_t avail  = ws_size / 4 > off ? ws_size / 4 - off : 0;
    int chunk = (int)(avail / perB_f);
    if (chunk > B_) chunk = B_;
    if (chunk < 1) chunk = 1;
    unsigned short* evT = (unsigned short*)(ws + off);
    unsigned short* Tb  = evT + (size_t)chunk * PPAD * C_;

    hipMemsetAsync(ws, 0, zero_count * sizeof(float), stream);

    k_prepA<<<576, 256, 0, stream>>>(Wv, Abf);

    if (chunk >= B_) {
        dim3 gt(PPAD / 64, C_ / 64, B_);
        k_transpose64<<<gt, 256, 0, stream>>>(ev, evT, evmean, 1, 0);
    } else {
        k_evmean<<<B_ * C_ / 4, 256, 0, stream>>>(ev, evmean);
    }

    // audio chain (split-K for occupancy)
    k32<0, 0, 0, 4><<<dim3(8, 3, 4), 256, 0, stream>>>(ea, Wa1, Hb, B_, C_, 2048);
    k32<0, 1, 0, 2><<<dim3(8, 3, 2), 256, 0, stream>>>(Hb, Wa2, fa, B_, C_, C_);

    // visual chain
    k32<0, 0, 0, 2><<<dim3(8, 3, 2), 256, 0, stream>>>(evmean, Wv, ind_vec, B_, C_, C_);
    k_rownorm<<<B_, 64, 0, stream>>>(ind_vec, iv_norm);
    k32<1, 0, 1, 1><<<dim3(8, 3, 1), 256, 0, stream>>>(iv_norm, Wv, Abf + (size_t)512 * C_, B_, C_, C_);

    if (chunk >= B_) {
        // 4 quarter dispatches: profiler diagnostic (any kernel >~52us surfaces in top-5)
        for (int q = 0; q < 4; q++) {
            int b0 = q * 48;
            int grid = 8 * ((48 * 42 + 7) / 8);
            k_gemm<<<grid, 256, 0, stream>>>(Abf, evT, n2, Tb, b0, 48);
        }
        int n = B_ * HW_;
        k_invn<<<(n + 255) / 256, 256, 0, stream>>>(n2, invn, n);
        dim3 gp(B_ / 4, B_);
        k_pool<<<gp, 256, 0, stream>>>(Tb, invn, SPb, SNb, 0);
    } else {
        for (int b0 = 0; b0 < B_; b0 += chunk) {
            int nb = (B_ - b0 < chunk) ? (B_ - b0) : chunk;
            dim3 gt(PPAD / 64, C_ / 64, nb);
            k_transpose64<<<gt, 256, 0, stream>>>(ev, evT, evmean, 0, b0);
            // note: fallback path writes evT/Tb chunked at offset 0
            int grid = 8 * ((nb * 42 + 7) / 8);
            k_gemm<<<grid, 256, 0, stream>>>(Abf, evT - (size_t)b0 * PPAD * C_, n2,
                                             Tb - (size_t)b0 * B_ * HW_, b0, nb);
            int n = nb * HW_;
            k_invn<<<(n + 255) / 256, 256, 0, stream>>>(n2 + (size_t)b0 * HW_,
                                                        invn + (size_t)b0 * HW_, n);
            dim3 gp(B_ / 4, nb);
            k_pool<<<gp, 256, 0, stream>>>(Tb - (size_t)b0 * B_ * HW_, invn, SPb, SNb, b0);
        }
    }

    k_loss12<<<B_, 128, 0, stream>>>(SPb, SNb, accb);
    dim3 gd(B_ / 64, B_ / 64);
    k_distfin<<<gd, 256, 0, stream>>>(ind_vec, iv_norm, fa, accb, rowsum, colsum, cntp, out);
}

// Round 8
// 512.642 us; speedup vs baseline: 1.1324x; 1.1324x over previous
//
#include <hip/hip_runtime.h>
#include <hip/hip_fp8.h>
#include <math.h>

#define B_   192
#define C_   512
#define HW_  784
#define TPK  23          // int(784*0.03)
#define PPAD 896         // 7 p-tiles of 128

typedef __attribute__((ext_vector_type(4))) float f4;
typedef __attribute__((ext_vector_type(8))) unsigned char uc8;

__device__ __forceinline__ float sigf(float x) {
    return 1.0f / (1.0f + __expf(-x));
}
__device__ __forceinline__ unsigned short f2bf(float f) {
    unsigned u = __float_as_uint(f);
    unsigned r = u + 0x7FFFu + ((u >> 16) & 1u);
    return (unsigned short)(r >> 16);
}
__device__ __forceinline__ float bf2f(unsigned short u) {
    return __uint_as_float(((unsigned)u) << 16);
}
__device__ __forceinline__ unsigned char f2fp8(float x) {
    __hip_fp8_e4m3 t(x);                 // OCP e4m3fn, RNE
    return (unsigned char)t.__x;
}
__device__ __forceinline__ void gld16(const void* g, void* l) {
    __builtin_amdgcn_global_load_lds((const __attribute__((address_space(1))) unsigned int*)g,
                                     (__attribute__((address_space(3))) unsigned int*)l, 16, 0, 0);
}

// ---------------------------------------------------------------- evmean (fallback only)
__global__ void k_evmean(const float* __restrict__ ev, float* __restrict__ evmean) {
    int row  = blockIdx.x * 4 + (threadIdx.x >> 6);
    int lane = threadIdx.x & 63;
    const float4* s4 = (const float4*)(ev + (size_t)row * HW_);
    float s = 0.f;
    for (int i = lane; i < HW_ / 4; i += 64) {
        float4 v = s4[i];
        s += v.x + v.y + v.z + v.w;
    }
    for (int off = 32; off > 0; off >>= 1) s += __shfl_down(s, off, 64);
    if (lane == 0) evmean[row] = s * (1.0f / HW_);
}

// ---------------------------------------------------------------- tiled fp32 GEMM w/ split-K
template<int BKN, int RELUA, int SPLITK>
__global__ __launch_bounds__(256)
void k32(const float* __restrict__ A, const float* __restrict__ B,
         float* __restrict__ C, int M, int N, int K) {
    __shared__ float As[16][68];
    __shared__ float Bs[16][68];
    int m0 = blockIdx.y * 64, n0 = blockIdx.x * 64;
    int kslice = K / SPLITK;
    int kbeg = blockIdx.z * kslice;
    int tid = threadIdx.x;
    int tx = tid & 15, ty = tid >> 4;
    int r = tid >> 2, c4 = tid & 3;

    float acc[4][4];
#pragma unroll
    for (int i = 0; i < 4; i++)
#pragma unroll
        for (int j = 0; j < 4; j++) acc[i][j] = 0.f;

    for (int k0 = kbeg; k0 < kbeg + kslice; k0 += 16) {
        float4 av = *(const float4*)(A + (size_t)(m0 + r) * K + k0 + c4 * 4);
        if (RELUA) {
            av.x = fmaxf(av.x, 0.f); av.y = fmaxf(av.y, 0.f);
            av.z = fmaxf(av.z, 0.f); av.w = fmaxf(av.w, 0.f);
        }
        As[c4 * 4 + 0][r] = av.x; As[c4 * 4 + 1][r] = av.y;
        As[c4 * 4 + 2][r] = av.z; As[c4 * 4 + 3][r] = av.w;
        if (BKN == 0) {
            float4 bv = *(const float4*)(B + (size_t)(n0 + r) * K + k0 + c4 * 4);
            Bs[c4 * 4 + 0][r] = bv.x; Bs[c4 * 4 + 1][r] = bv.y;
            Bs[c4 * 4 + 2][r] = bv.z; Bs[c4 * 4 + 3][r] = bv.w;
        } else {
            float4 bv = *(const float4*)(B + (size_t)(k0 + ty) * N + n0 + tx * 4);
            Bs[ty][tx * 4 + 0] = bv.x; Bs[ty][tx * 4 + 1] = bv.y;
            Bs[ty][tx * 4 + 2] = bv.z; Bs[ty][tx * 4 + 3] = bv.w;
        }
        __syncthreads();
#pragma unroll
        for (int kk = 0; kk < 16; kk++) {
            float a_[4];
#pragma unroll
            for (int i = 0; i < 4; i++) a_[i] = As[kk][ty * 4 + i];
            float4 bb = *(const float4*)&Bs[kk][tx * 4];
#pragma unroll
            for (int i = 0; i < 4; i++) {
                acc[i][0] = fmaf(a_[i], bb.x, acc[i][0]);
                acc[i][1] = fmaf(a_[i], bb.y, acc[i][1]);
                acc[i][2] = fmaf(a_[i], bb.z, acc[i][2]);
                acc[i][3] = fmaf(a_[i], bb.w, acc[i][3]);
            }
        }
        __syncthreads();
    }
#pragma unroll
    for (int i = 0; i < 4; i++) {
        if (SPLITK > 1) {
            float* row = C + (size_t)(m0 + ty * 4 + i) * N + n0 + tx * 4;
#pragma unroll
            for (int j = 0; j < 4; j++) atomicAdd(&row[j], acc[i][j]);
        } else {
            *(float4*)(C + (size_t)(m0 + ty * 4 + i) * N + n0 + tx * 4) =
                make_float4(acc[i][0], acc[i][1], acc[i][2], acc[i][3]);
        }
    }
}

// ---------------------------------------------------------------- iv_norm = l2norm(ind_vec) per row
__global__ void k_rownorm(const float* __restrict__ iv, float* __restrict__ ivn) {
    int b = blockIdx.x, lane = threadIdx.x;
    float v[8]; float s = 0.f;
#pragma unroll
    for (int k = 0; k < 8; k++) {
        v[k] = iv[(size_t)b * C_ + lane + 64 * k];
        s = fmaf(v[k], v[k], s);
    }
#pragma unroll
    for (int off = 32; off > 0; off >>= 1) s += __shfl_xor(s, off, 64);
    float rn = 1.0f / fmaxf(sqrtf(s), 1e-12f);
#pragma unroll
    for (int k = 0; k < 8; k++) ivn[(size_t)b * C_ + lane + 64 * k] = v[k] * rn;
}

// ---------------------------------------------------------------- Abf: rows 0..511 = fp8(Wv), 704..767 = 0
__global__ void k_prepA(const float* __restrict__ Wv, unsigned char* __restrict__ Abf) {
    int r = blockIdx.x, tid = threadIdx.x;
    int row = (r < 512) ? r : (192 + r);   // 512..575 -> 704..767 zero pad
    for (int i = 0; i < 2; i++) {
        int c = tid + i * 256;
        float v = (r < 512) ? Wv[(size_t)r * C_ + c] : 0.f;
        Abf[(size_t)row * C_ + c] = f2fp8(v);
    }
}

// ---------------------------------------------------------------- U rows of Abf: fp8(ivn @ Wv), K=512
__global__ __launch_bounds__(256)
void k_Ufp8(const float* __restrict__ ivn, const float* __restrict__ Wv,
            unsigned char* __restrict__ Abf) {
    __shared__ float As[16][68];
    __shared__ float Bs[16][68];
    int m0 = blockIdx.y * 64, n0 = blockIdx.x * 64;
    int tid = threadIdx.x;
    int tx = tid & 15, ty = tid >> 4;
    int r = tid >> 2, c4 = tid & 3;
    float acc[4][4];
#pragma unroll
    for (int i = 0; i < 4; i++)
#pragma unroll
        for (int j = 0; j < 4; j++) acc[i][j] = 0.f;
    for (int k0 = 0; k0 < C_; k0 += 16) {
        float4 av = *(const float4*)(ivn + (size_t)(m0 + r) * C_ + k0 + c4 * 4);
        As[c4 * 4 + 0][r] = av.x; As[c4 * 4 + 1][r] = av.y;
        As[c4 * 4 + 2][r] = av.z; As[c4 * 4 + 3][r] = av.w;
        float4 bv = *(const float4*)(Wv + (size_t)(k0 + ty) * C_ + n0 + tx * 4);
        Bs[ty][tx * 4 + 0] = bv.x; Bs[ty][tx * 4 + 1] = bv.y;
        Bs[ty][tx * 4 + 2] = bv.z; Bs[ty][tx * 4 + 3] = bv.w;
        __syncthreads();
#pragma unroll
        for (int kk = 0; kk < 16; kk++) {
            float a_[4];
#pragma unroll
            for (int i = 0; i < 4; i++) a_[i] = As[kk][ty * 4 + i];
            float4 bb = *(const float4*)&Bs[kk][tx * 4];
#pragma unroll
            for (int i = 0; i < 4; i++) {
                acc[i][0] = fmaf(a_[i], bb.x, acc[i][0]);
                acc[i][1] = fmaf(a_[i], bb.y, acc[i][1]);
                acc[i][2] = fmaf(a_[i], bb.z, acc[i][2]);
                acc[i][3] = fmaf(a_[i], bb.w, acc[i][3]);
            }
        }
        __syncthreads();
    }
#pragma unroll
    for (int i = 0; i < 4; i++) {
        unsigned char* row = Abf + (size_t)(512 + m0 + ty * 4 + i) * C_ + n0 + tx * 4;
#pragma unroll
        for (int j = 0; j < 4; j++) row[j] = f2fp8(acc[i][j]);
    }
}

// ---------------------------------------------------------------- ev[b][c][p] fp32 -> evT[bl][p][c] fp8 (64x64 tiles)
__global__ __launch_bounds__(256)
void k_transpose64(const float* __restrict__ ev, unsigned char* __restrict__ evT,
                   float* __restrict__ evsum, int doevm, int b0) {
    __shared__ float t[64][67];
    int bl = blockIdx.z, b = b0 + bl;
    int c0 = blockIdx.y * 64, p0 = blockIdx.x * 64;
    int tid = threadIdx.x;
    int cl = tid >> 4;
    int pc = tid & 15;
    int p = p0 + pc * 4;
#pragma unroll
    for (int q = 0; q < 4; q++) {
        int c_local = q * 16 + cl;
        const float* src = ev + ((size_t)b * C_ + c0 + c_local) * HW_;
        float4 v = make_float4(0.f, 0.f, 0.f, 0.f);
        if (p + 3 < HW_) v = *(const float4*)(src + p);
        else if (p < HW_) { for (int j = 0; j < 4; j++) if (p + j < HW_) ((float*)&v)[j] = src[p + j]; }
        if (doevm) {
            float rs = v.x + v.y + v.z + v.w;
            rs += __shfl_xor(rs, 1, 16);
            rs += __shfl_xor(rs, 2, 16);
            rs += __shfl_xor(rs, 4, 16);
            rs += __shfl_xor(rs, 8, 16);
            if (pc == 0) atomicAdd(&evsum[b * C_ + c0 + c_local], rs * (1.0f / HW_));
        }
        t[c_local][pc * 4 + 0] = v.x; t[c_local][pc * 4 + 1] = v.y;
        t[c_local][pc * 4 + 2] = v.z; t[c_local][pc * 4 + 3] = v.w;
    }
    __syncthreads();
    int r = tid >> 3;   // 0..31 p-row
    int j = tid & 7;    // c-chunk of 8
#pragma unroll
    for (int q = 0; q < 2; q++) {
        int row = r + q * 32;
        uc8 o;
#pragma unroll
        for (int k = 0; k < 8; k++) o[k] = f2fp8(t[j * 8 + k][row]);
        *(uc8*)(evT + ((size_t)bl * PPAD + p0 + row) * C_ + c0 + j * 8) = o;
    }
}

// ---------------------------------------------------------------- MFMA GEMM (fp8 e4m3): [Wv;U](704x512) @ ev[b](512x784)
// tiles 128x128, BK=32, 4 waves 2x2, 16x16x32_fp8_fp8
__global__ __launch_bounds__(256, 4)
void k_gemm(const unsigned char* __restrict__ Abf, const unsigned char* __restrict__ evT,
            float* __restrict__ n2, unsigned short* __restrict__ Tb, int b0, int nb) {
    __shared__ unsigned char As[2][4096];   // [128][32] fp8
    __shared__ unsigned char Bs[2][4096];

    int id = blockIdx.x;
    int xcd = id & 7, slot = id >> 3;
    int S = (nb * 42 + 7) >> 3;
    int w = xcd * S + slot;
    if (w >= nb * 42) return;
    int bl = w / 42, rem = w % 42;
    int pt = rem / 6, ot = rem % 6;
    int o0 = ot * 128, p0 = pt * 128;

    int tid = threadIdx.x;
    int wid = tid >> 6, lane = tid & 63;
    int wy = wid >> 1, wx = wid & 1;
    int l15 = lane & 15, l4 = lane >> 4;

    // staging: 128 rows x 32B per tile = 4KB = 256 threads x 16B (one gld16 each)
    const unsigned char* Ag = Abf + ((size_t)o0 + (tid >> 1)) * C_ + (tid & 1) * 16;
    const unsigned char* Bg = evT + ((size_t)(b0 + bl) * PPAD + p0 + (tid >> 1)) * C_ + (tid & 1) * 16;
    int lds_off = tid * 16;

    f4 acc[4][4] = {};
    int cur = 0;

#define STAGE(buf, k0) do { \
    gld16(Ag + (k0), &As[buf][0] + lds_off); \
    gld16(Bg + (k0), &Bs[buf][0] + lds_off); \
} while (0)

    STAGE(0, 0);
    __syncthreads();
    for (int t = 0; t < 16; ++t) {
        if (t < 15) STAGE(cur ^ 1, (t + 1) * 32);
        const long* Ar = (const long*)&As[cur][0];
        const long* Br = (const long*)&Bs[cur][0];
        long a[4], b[4];
#pragma unroll
        for (int mi = 0; mi < 4; mi++) a[mi] = Ar[(wy * 64 + mi * 16 + l15) * 4 + l4];
#pragma unroll
        for (int ni = 0; ni < 4; ni++) b[ni] = Br[(wx * 64 + ni * 16 + l15) * 4 + l4];
#pragma unroll
        for (int mi = 0; mi < 4; mi++)
#pragma unroll
            for (int ni = 0; ni < 4; ni++)
                acc[mi][ni] = __builtin_amdgcn_mfma_f32_16x16x32_fp8_fp8(a[mi], b[ni], acc[mi][ni], 0, 0, 0);
        __syncthreads();
        cur ^= 1;
    }
#undef STAGE

    if (ot < 4) {
        float* red = (float*)&As[0][0];
#pragma unroll
        for (int ni = 0; ni < 4; ni++) {
            float s = 0.f;
#pragma unroll
            for (int mi = 0; mi < 4; mi++)
#pragma unroll
                for (int r = 0; r < 4; r++) { float x = acc[mi][ni][r]; s = fmaf(x, x, s); }
            red[(wy * 4 + l4) * 128 + wx * 64 + ni * 16 + l15] = s;
        }
        __syncthreads();
        if (tid < 128) {
            float s = 0.f;
#pragma unroll
            for (int q = 0; q < 8; q++) s += red[q * 128 + tid];
            int p = p0 + tid;
            if (p < HW_) atomicAdd(&n2[(size_t)(b0 + bl) * HW_ + p], s);
        }
    } else {
        int dbase = o0 - 512 + wy * 64;
#pragma unroll
        for (int mi = 0; mi < 4; mi++)
#pragma unroll
            for (int r = 0; r < 4; r++) {
                int dd = dbase + mi * 16 + l4 * 4 + r;
                if (dd < B_) {
                    size_t rowoff = ((size_t)(b0 + bl) * B_ + dd) * HW_;
#pragma unroll
                    for (int ni = 0; ni < 4; ni++) {
                        int p = p0 + wx * 64 + ni * 16 + l15;
                        if (p < HW_) Tb[rowoff + p] = f2bf(acc[mi][ni][r]);
                    }
                }
            }
    }
}

// ---------------------------------------------------------------- invn[b,p] = 1/max(sqrt(n2),1e-12)
__global__ void k_invn(const float* __restrict__ n2, float* __restrict__ invn, int n) {
    int i = blockIdx.x * 256 + threadIdx.x;
    if (i >= n) return;
    invn[i] = 1.0f / fmaxf(sqrtf(n2[i]), 1e-12f);
}

// ---------------------------------------------------------------- pool: wave per (b,d); dual interleaved bisection
__global__ __launch_bounds__(256)
void k_pool(const unsigned short* __restrict__ T, const float* __restrict__ invn,
            float* __restrict__ SP, float* __restrict__ SN, int b0) {
    int tid = threadIdx.x;
    int wv = tid >> 6, lane = tid & 63;
    int d = blockIdx.x * 4 + wv;
    int bl = blockIdx.y, b = b0 + bl;
    const unsigned short* Trow = T + ((size_t)b * B_ + d) * HW_;
    const float* nrow = invn + (size_t)b * HW_;
    float sv[13];
#pragma unroll
    for (int i = 0; i < 12; i++) {
        int p = lane + i * 64;
        sv[i] = bf2f(Trow[p]) * nrow[p];
    }
    {
        int p = lane + 768;
        sv[12] = (p < HW_) ? bf2f(Trow[p]) * nrow[p] : __uint_as_float(0x7FC00000u);
    }
    float vmax = -1e30f, vmin = 1e30f;
#pragma unroll
    for (int i = 0; i < 13; i++) { vmax = fmaxf(vmax, sv[i]); vmin = fminf(vmin, sv[i]); }
#pragma unroll
    for (int off = 32; off > 0; off >>= 1) {
        vmax = fmaxf(vmax, __shfl_xor(vmax, off, 64));
        vmin = fminf(vmin, __shfl_xor(vmin, off, 64));
    }
    float lo1 = vmin, hi1 = vmax, lo2 = vmin, hi2 = vmax;
    for (int it = 0; it < 13; ++it) {
        float m1 = 0.5f * (lo1 + hi1), m2 = 0.5f * (lo2 + hi2);
        int c1 = 0, c2 = 0;
#pragma unroll
        for (int i = 0; i < 13; i++) {
            c1 += __popcll(__ballot(sv[i] >= m1));
            c2 += __popcll(__ballot(sv[i] <= m2));
        }
        if (c1 >= TPK) lo1 = m1; else hi1 = m1;
        if (c2 >= TPK) hi2 = m2; else lo2 = m2;
    }
    float thrp = lo1, thrn = hi2;
    const float its = 1.0f / 0.03f;
    float spn = 0.f, spd = 0.f, snn = 0.f, snd = 0.f;
#pragma unroll
    for (int i = 0; i < 13; i++) {
        if (i == 12 && lane >= 16) continue;
        float s = sv[i];
        float mp = sigf((s - thrp) * its);
        float mn = sigf(-(s - thrn) * its);
        spn += s * mp; spd += mp;
        snn += s * mn; snd += mn;
    }
    for (int off = 32; off > 0; off >>= 1) {
        spn += __shfl_down(spn, off, 64);
        spd += __shfl_down(spd, off, 64);
        snn += __shfl_down(snn, off, 64);
        snd += __shfl_down(snd, off, 64);
    }
    if (lane == 0) {
        SP[b * B_ + d] = spn / spd;
        SN[b * B_ + d] = snn / snd;
    }
}

// ---------------------------------------------------------------- CE losses
__global__ void k_loss12(const float* __restrict__ SP, const float* __restrict__ SN,
                         float* __restrict__ acc) {
    __shared__ float red[128];
    int i = blockIdx.x, tid = threadIdx.x;
    const float itc = 1.0f / 0.07f;
    for (int phase = 0; phase < 2; phase++) {
        float mx = -INFINITY;
        for (int j = tid; j < 2 * B_; j += 128) {
            float v;
            if (phase == 0) v = (j < B_ ? SP[i * B_ + j] : SN[i * B_ + (j - B_)]);
            else            v = (j < B_ ? SP[j * B_ + i] : SN[(j - B_) * B_ + i]);
            mx = fmaxf(mx, v * itc);
        }
        red[tid] = mx; __syncthreads();
        for (int s = 64; s > 0; s >>= 1) { if (tid < s) red[tid] = fmaxf(red[tid], red[tid + s]); __syncthreads(); }
        mx = red[0]; __syncthreads();
        float se = 0.f;
        for (int j = tid; j < 2 * B_; j += 128) {
            float v;
            if (phase == 0) v = (j < B_ ? SP[i * B_ + j] : SN[i * B_ + (j - B_)]);
            else            v = (j < B_ ? SP[j * B_ + i] : SN[(j - B_) * B_ + i]);
            se += __expf(v * itc - mx);
        }
        red[tid] = se; __syncthreads();
        for (int s = 64; s > 0; s >>= 1) { if (tid < s) red[tid] += red[tid + s]; __syncthreads(); }
        if (tid == 0) {
            float lse = logf(red[0]) + mx;
            atomicAdd(&acc[phase], lse - SP[i * B_ + i] * itc);
        }
        __syncthreads();
    }
}

// ---------------------------------------------------------------- fused distance matrix + final (last block)
__global__ __launch_bounds__(256)
void k_distfin(const float* __restrict__ iv, const float* __restrict__ ivn,
               const float* __restrict__ fa, const float* __restrict__ acc,
               float* __restrict__ rowsum, float* __restrict__ colsum,
               int* __restrict__ cnt, float* __restrict__ out) {
    __shared__ float Ai[16][68], An[16][68], Bf[16][68], Bn[16][68];
    __shared__ float rred[64][17], cred[64][17];
    __shared__ float fr[256];
    __shared__ int lastf;
    int i0 = blockIdx.y * 64, j0 = blockIdx.x * 64;
    int tid = threadIdx.x;
    int tx = tid & 15, ty = tid >> 4;
    int r = tid >> 2, c4 = tid & 3;
    float accD[4][4], accV[4][4];
#pragma unroll
    for (int i = 0; i < 4; i++)
#pragma unroll
        for (int j = 0; j < 4; j++) { accD[i][j] = 0.f; accV[i][j] = 0.f; }

    for (int k0 = 0; k0 < C_; k0 += 16) {
        float4 v;
        v = *(const float4*)(iv + (size_t)(i0 + r) * C_ + k0 + c4 * 4);
        Ai[c4*4+0][r]=v.x; Ai[c4*4+1][r]=v.y; Ai[c4*4+2][r]=v.z; Ai[c4*4+3][r]=v.w;
        v = *(const float4*)(ivn + (size_t)(i0 + r) * C_ + k0 + c4 * 4);
        An[c4*4+0][r]=v.x; An[c4*4+1][r]=v.y; An[c4*4+2][r]=v.z; An[c4*4+3][r]=v.w;
        v = *(const float4*)(fa + (size_t)(j0 + r) * C_ + k0 + c4 * 4);
        Bf[c4*4+0][r]=v.x; Bf[c4*4+1][r]=v.y; Bf[c4*4+2][r]=v.z; Bf[c4*4+3][r]=v.w;
        v = *(const float4*)(ivn + (size_t)(j0 + r) * C_ + k0 + c4 * 4);
        Bn[c4*4+0][r]=v.x; Bn[c4*4+1][r]=v.y; Bn[c4*4+2][r]=v.z; Bn[c4*4+3][r]=v.w;
        __syncthreads();
#pragma unroll
        for (int kk = 0; kk < 16; kk++) {
            float ai[4], an[4];
#pragma unroll
            for (int i = 0; i < 4; i++) { ai[i] = Ai[kk][ty*4+i]; an[i] = An[kk][ty*4+i]; }
            float4 bf = *(const float4*)&Bf[kk][tx*4];
            float4 bn = *(const float4*)&Bn[kk][tx*4];
#pragma unroll
            for (int i = 0; i < 4; i++) {
                float d0 = ai[i] - bf.x + 1e-6f; accD[i][0] = fmaf(d0, d0, accD[i][0]);
                float d1 = ai[i] - bf.y + 1e-6f; accD[i][1] = fmaf(d1, d1, accD[i][1]);
                float d2 = ai[i] - bf.z + 1e-6f; accD[i][2] = fmaf(d2, d2, accD[i][2]);
                float d3 = ai[i] - bf.w + 1e-6f; accD[i][3] = fmaf(d3, d3, accD[i][3]);
                accV[i][0] = fmaf(an[i], bn.x, accV[i][0]);
                accV[i][1] = fmaf(an[i], bn.y, accV[i][1]);
                accV[i][2] = fmaf(an[i], bn.z, accV[i][2]);
                accV[i][3] = fmaf(an[i], bn.w, accV[i][3]);
            }
        }
        __syncthreads();
    }
    float rp[4] = {0.f, 0.f, 0.f, 0.f};
    float cp[4] = {0.f, 0.f, 0.f, 0.f};
#pragma unroll
    for (int i = 0; i < 4; i++)
#pragma unroll
        for (int j = 0; j < 4; j++) {
            int gi = i0 + ty * 4 + i, gj = j0 + tx * 4 + j;
            float val = (gi == gj) ? accD[i][j] : accD[i][j] * accV[i][j] * (1.0f / 191.0f);
            rp[i] += val; cp[j] += val;
        }
#pragma unroll
    for (int i = 0; i < 4; i++) rred[ty * 4 + i][tx] = rp[i];
#pragma unroll
    for (int j = 0; j < 4; j++) cred[tx * 4 + j][ty] = cp[j];
    __syncthreads();
    if (tid < 64) {
        float s = 0.f;
#pragma unroll
        for (int q = 0; q < 16; q++) s += rred[tid][q];
        atomicAdd(&rowsum[i0 + tid], s);
    } else if (tid < 128) {
        int t = tid - 64;
        float s = 0.f;
#pragma unroll
        for (int q = 0; q < 16; q++) s += cred[t][q];
        atomicAdd(&colsum[j0 + t], s);
    }
    __threadfence();
    __syncthreads();
    if (tid == 0) lastf = (atomicAdd(cnt, 1) == 8);
    __syncthreads();
    if (lastf) {
        __threadfence();
        float v3 = (tid < B_) ? fmaxf(rowsum[tid] + 0.6f, 0.f) : 0.f;
        float v4 = (tid < B_) ? fmaxf(colsum[tid] + 0.6f, 0.f) : 0.f;
        fr[tid] = v3; __syncthreads();
        for (int s = 128; s > 0; s >>= 1) { if (tid < s) fr[tid] += fr[tid + s]; __syncthreads(); }
        float l3 = fr[0] / B_;
        __syncthreads();
        fr[tid] = v4; __syncthreads();
        for (int s = 128; s > 0; s >>= 1) { if (tid < s) fr[tid] += fr[tid + s]; __syncthreads(); }
        float l4 = fr[0] / B_;
        if (tid == 0) {
            out[0] = 0.5f * (acc[0] + acc[1]) / B_;
            out[1] = 0.5f * (l3 + l4);
        }
    }
}

extern "C" void kernel_launch(void* const* d_in, const int* in_sizes, int n_in,
                              void* d_out, int out_size, void* d_ws, size_t ws_size,
                              hipStream_t stream) {
    const float* ev  = (const float*)d_in[0];
    const float* ea  = (const float*)d_in[1];
    const float* Wv  = (const float*)d_in[2];
    const float* Wa1 = (const float*)d_in[3];
    const float* Wa2 = (const float*)d_in[4];
    float* out = (float*)d_out;
    float* ws  = (float*)d_ws;

    size_t off = 0;
    // contiguous zero block: evmean..fa, n2, acc/rowsum/colsum/cnt
    float* evmean  = ws + off; off += B_ * C_;
    float* ind_vec = ws + off; off += B_ * C_;
    float* Hb      = ws + off; off += B_ * C_;
    float* fa      = ws + off; off += B_ * C_;
    float* n2      = ws + off; off += B_ * HW_;
    float* accb    = ws + off;
    float* rowsum  = accb + 16;
    float* colsum  = rowsum + B_;
    int*   cntp    = (int*)(colsum + B_);
    off += 16 + B_ + B_ + 16;
    size_t zero_count = off;
    float* iv_norm = ws + off; off += B_ * C_;
    float* invn    = ws + off; off += B_ * HW_;
    float* SPb     = ws + off; off += B_ * B_;
    float* SNb     = ws + off; off += B_ * B_;
    unsigned char* Abf = (unsigned char*)(ws + off); off += 768 * C_ / 4;   // fp8 bytes

    // per-b: evT fp8 (PPAD*C_ bytes = PPAD*C_/4 floats) + Tb bf16 (B_*HW_/2 floats)
    size_t perB_f = (size_t)PPAD * C_ / 4 + (size_t)B_ * HW_ / 2;
    size_t avail  = ws_size / 4 > off ? ws_size / 4 - off : 0;
    int chunk = (int)(avail / perB_f);
    if (chunk > B_) chunk = B_;
    if (chunk < 1) chunk = 1;
    unsigned char* evT = (unsigned char*)(ws + off);
    unsigned short* Tb = (unsigned short*)(evT + (size_t)chunk * PPAD * C_);

    hipMemsetAsync(ws, 0, zero_count * sizeof(float), stream);

    k_prepA<<<576, 256, 0, stream>>>(Wv, Abf);

    if (chunk >= B_) {
        dim3 gt(PPAD / 64, C_ / 64, B_);
        k_transpose64<<<gt, 256, 0, stream>>>(ev, evT, evmean, 1, 0);
    } else {
        k_evmean<<<B_ * C_ / 4, 256, 0, stream>>>(ev, evmean);
    }

    // audio chain (split-K for occupancy)
    k32<0, 0, 4><<<dim3(8, 3, 4), 256, 0, stream>>>(ea, Wa1, Hb, B_, C_, 2048);
    k32<0, 1, 2><<<dim3(8, 3, 2), 256, 0, stream>>>(Hb, Wa2, fa, B_, C_, C_);

    // visual chain
    k32<0, 0, 2><<<dim3(8, 3, 2), 256, 0, stream>>>(evmean, Wv, ind_vec, B_, C_, C_);
    k_rownorm<<<B_, 64, 0, stream>>>(ind_vec, iv_norm);
    k_Ufp8<<<dim3(8, 3), 256, 0, stream>>>(iv_norm, Wv, Abf);

    if (chunk >= B_) {
        int grid = 8 * ((B_ * 42 + 7) / 8);
        k_gemm<<<grid, 256, 0, stream>>>(Abf, evT, n2, Tb, 0, B_);
        int n = B_ * HW_;
        k_invn<<<(n + 255) / 256, 256, 0, stream>>>(n2, invn, n);
        dim3 gp(B_ / 4, B_);
        k_pool<<<gp, 256, 0, stream>>>(Tb, invn, SPb, SNb, 0);
    } else {
        for (int b0 = 0; b0 < B_; b0 += chunk) {
            int nb = (B_ - b0 < chunk) ? (B_ - b0) : chunk;
            dim3 gt(PPAD / 64, C_ / 64, nb);
            k_transpose64<<<gt, 256, 0, stream>>>(ev, evT, evmean, 0, b0);
            int grid = 8 * ((nb * 42 + 7) / 8);
            k_gemm<<<grid, 256, 0, stream>>>(Abf, evT - (size_t)b0 * PPAD * C_, n2,
                                             Tb - (size_t)b0 * B_ * HW_, b0, nb);
            int n = nb * HW_;
            k_invn<<<(n + 255) / 256, 256, 0, stream>>>(n2 + (size_t)b0 * HW_,
                                                        invn + (size_t)b0 * HW_, n);
            dim3 gp(B_ / 4, nb);
            k_pool<<<gp, 256, 0, stream>>>(Tb - (size_t)b0 * B_ * HW_, invn, SPb, SNb, b0);
        }
    }

    k_loss12<<<B_, 128, 0, stream>>>(SPb, SNb, accb);
    dim3 gd(B_ / 64, B_ / 64);
    k_distfin<<<gd, 256, 0, stream>>>(ind_vec, iv_norm, fa, accb, rowsum, colsum, cntp, out);
}

// Round 9
// 484.382 us; speedup vs baseline: 1.1984x; 1.0583x over previous
//
#include <hip/hip_runtime.h>
#include <hip/hip_fp8.h>
#include <math.h>

#define B_   192
#define C_   512
#define HW_  784
#define TPK  23          // int(784*0.03)
#define NTOT (B_ * HW_)  // 150528 = 1176 * 128 exactly

typedef __attribute__((ext_vector_type(4))) float f4;
typedef __attribute__((ext_vector_type(8))) unsigned char uc8;

__device__ __forceinline__ float sigf(float x) {
    return 1.0f / (1.0f + __expf(-x));
}
__device__ __forceinline__ unsigned short f2bf(float f) {
    unsigned u = __float_as_uint(f);
    unsigned r = u + 0x7FFFu + ((u >> 16) & 1u);
    return (unsigned short)(r >> 16);
}
__device__ __forceinline__ float bf2f(unsigned short u) {
    return __uint_as_float(((unsigned)u) << 16);
}
__device__ __forceinline__ unsigned char f2fp8(float x) {
    __hip_fp8_e4m3 t(x);                 // OCP e4m3fn, RNE
    return (unsigned char)t.__x;
}
__device__ __forceinline__ void gld16(const void* g, void* l) {
    __builtin_amdgcn_global_load_lds((const __attribute__((address_space(1))) unsigned int*)g,
                                     (__attribute__((address_space(3))) unsigned int*)l, 16, 0, 0);
}

// ---------------------------------------------------------------- evmean (fallback only)
__global__ void k_evmean(const float* __restrict__ ev, float* __restrict__ evmean) {
    int row  = blockIdx.x * 4 + (threadIdx.x >> 6);
    int lane = threadIdx.x & 63;
    const float4* s4 = (const float4*)(ev + (size_t)row * HW_);
    float s = 0.f;
    for (int i = lane; i < HW_ / 4; i += 64) {
        float4 v = s4[i];
        s += v.x + v.y + v.z + v.w;
    }
    for (int off = 32; off > 0; off >>= 1) s += __shfl_down(s, off, 64);
    if (lane == 0) evmean[row] = s * (1.0f / HW_);
}

// ---------------------------------------------------------------- tiled fp32 GEMM w/ split-K
template<int BKN, int RELUA, int SPLITK>
__global__ __launch_bounds__(256)
void k32(const float* __restrict__ A, const float* __restrict__ B,
         float* __restrict__ C, int M, int N, int K) {
    __shared__ float As[16][68];
    __shared__ float Bs[16][68];
    int m0 = blockIdx.y * 64, n0 = blockIdx.x * 64;
    int kslice = K / SPLITK;
    int kbeg = blockIdx.z * kslice;
    int tid = threadIdx.x;
    int tx = tid & 15, ty = tid >> 4;
    int r = tid >> 2, c4 = tid & 3;

    float acc[4][4];
#pragma unroll
    for (int i = 0; i < 4; i++)
#pragma unroll
        for (int j = 0; j < 4; j++) acc[i][j] = 0.f;

    for (int k0 = kbeg; k0 < kbeg + kslice; k0 += 16) {
        float4 av = *(const float4*)(A + (size_t)(m0 + r) * K + k0 + c4 * 4);
        if (RELUA) {
            av.x = fmaxf(av.x, 0.f); av.y = fmaxf(av.y, 0.f);
            av.z = fmaxf(av.z, 0.f); av.w = fmaxf(av.w, 0.f);
        }
        As[c4 * 4 + 0][r] = av.x; As[c4 * 4 + 1][r] = av.y;
        As[c4 * 4 + 2][r] = av.z; As[c4 * 4 + 3][r] = av.w;
        if (BKN == 0) {
            float4 bv = *(const float4*)(B + (size_t)(n0 + r) * K + k0 + c4 * 4);
            Bs[c4 * 4 + 0][r] = bv.x; Bs[c4 * 4 + 1][r] = bv.y;
            Bs[c4 * 4 + 2][r] = bv.z; Bs[c4 * 4 + 3][r] = bv.w;
        } else {
            float4 bv = *(const float4*)(B + (size_t)(k0 + ty) * N + n0 + tx * 4);
            Bs[ty][tx * 4 + 0] = bv.x; Bs[ty][tx * 4 + 1] = bv.y;
            Bs[ty][tx * 4 + 2] = bv.z; Bs[ty][tx * 4 + 3] = bv.w;
        }
        __syncthreads();
#pragma unroll
        for (int kk = 0; kk < 16; kk++) {
            float a_[4];
#pragma unroll
            for (int i = 0; i < 4; i++) a_[i] = As[kk][ty * 4 + i];
            float4 bb = *(const float4*)&Bs[kk][tx * 4];
#pragma unroll
            for (int i = 0; i < 4; i++) {
                acc[i][0] = fmaf(a_[i], bb.x, acc[i][0]);
                acc[i][1] = fmaf(a_[i], bb.y, acc[i][1]);
                acc[i][2] = fmaf(a_[i], bb.z, acc[i][2]);
                acc[i][3] = fmaf(a_[i], bb.w, acc[i][3]);
            }
        }
        __syncthreads();
    }
#pragma unroll
    for (int i = 0; i < 4; i++) {
        if (SPLITK > 1) {
            float* row = C + (size_t)(m0 + ty * 4 + i) * N + n0 + tx * 4;
#pragma unroll
            for (int j = 0; j < 4; j++) atomicAdd(&row[j], acc[i][j]);
        } else {
            *(float4*)(C + (size_t)(m0 + ty * 4 + i) * N + n0 + tx * 4) =
                make_float4(acc[i][0], acc[i][1], acc[i][2], acc[i][3]);
        }
    }
}

// ---------------------------------------------------------------- iv_norm = l2norm(ind_vec) per row
__global__ void k_rownorm(const float* __restrict__ iv, float* __restrict__ ivn) {
    int b = blockIdx.x, lane = threadIdx.x;
    float v[8]; float s = 0.f;
#pragma unroll
    for (int k = 0; k < 8; k++) {
        v[k] = iv[(size_t)b * C_ + lane + 64 * k];
        s = fmaf(v[k], v[k], s);
    }
#pragma unroll
    for (int off = 32; off > 0; off >>= 1) s += __shfl_xor(s, off, 64);
    float rn = 1.0f / fmaxf(sqrtf(s), 1e-12f);
#pragma unroll
    for (int k = 0; k < 8; k++) ivn[(size_t)b * C_ + lane + 64 * k] = v[k] * rn;
}

// ---------------------------------------------------------------- Abf: rows 0..511 = fp8(Wv), 704..767 = 0
__global__ void k_prepA(const float* __restrict__ Wv, unsigned char* __restrict__ Abf) {
    int r = blockIdx.x, tid = threadIdx.x;
    int row = (r < 512) ? r : (192 + r);   // 512..575 -> 704..767 zero pad
    for (int i = 0; i < 2; i++) {
        int c = tid + i * 256;
        float v = (r < 512) ? Wv[(size_t)r * C_ + c] : 0.f;
        Abf[(size_t)row * C_ + c] = f2fp8(v);
    }
}

// ---------------------------------------------------------------- U rows of Abf: fp8(ivn @ Wv), K=512
__global__ __launch_bounds__(256)
void k_Ufp8(const float* __restrict__ ivn, const float* __restrict__ Wv,
            unsigned char* __restrict__ Abf) {
    __shared__ float As[16][68];
    __shared__ float Bs[16][68];
    int m0 = blockIdx.y * 64, n0 = blockIdx.x * 64;
    int tid = threadIdx.x;
    int tx = tid & 15, ty = tid >> 4;
    int r = tid >> 2, c4 = tid & 3;
    float acc[4][4];
#pragma unroll
    for (int i = 0; i < 4; i++)
#pragma unroll
        for (int j = 0; j < 4; j++) acc[i][j] = 0.f;
    for (int k0 = 0; k0 < C_; k0 += 16) {
        float4 av = *(const float4*)(ivn + (size_t)(m0 + r) * C_ + k0 + c4 * 4);
        As[c4 * 4 + 0][r] = av.x; As[c4 * 4 + 1][r] = av.y;
        As[c4 * 4 + 2][r] = av.z; As[c4 * 4 + 3][r] = av.w;
        float4 bv = *(const float4*)(Wv + (size_t)(k0 + ty) * C_ + n0 + tx * 4);
        Bs[ty][tx * 4 + 0] = bv.x; Bs[ty][tx * 4 + 1] = bv.y;
        Bs[ty][tx * 4 + 2] = bv.z; Bs[ty][tx * 4 + 3] = bv.w;
        __syncthreads();
#pragma unroll
        for (int kk = 0; kk < 16; kk++) {
            float a_[4];
#pragma unroll
            for (int i = 0; i < 4; i++) a_[i] = As[kk][ty * 4 + i];
            float4 bb = *(const float4*)&Bs[kk][tx * 4];
#pragma unroll
            for (int i = 0; i < 4; i++) {
                acc[i][0] = fmaf(a_[i], bb.x, acc[i][0]);
                acc[i][1] = fmaf(a_[i], bb.y, acc[i][1]);
                acc[i][2] = fmaf(a_[i], bb.z, acc[i][2]);
                acc[i][3] = fmaf(a_[i], bb.w, acc[i][3]);
            }
        }
        __syncthreads();
    }
#pragma unroll
    for (int i = 0; i < 4; i++) {
        unsigned char* row = Abf + (size_t)(512 + m0 + ty * 4 + i) * C_ + n0 + tx * 4;
#pragma unroll
        for (int j = 0; j < 4; j++) row[j] = f2fp8(acc[i][j]);
    }
}

// ---------------------------------------------------------------- ev[b][c][p] fp32 -> evT[bl*784+p][c] fp8 (FLAT, no pad)
__global__ __launch_bounds__(256)
void k_transpose64(const float* __restrict__ ev, unsigned char* __restrict__ evT,
                   float* __restrict__ evsum, int doevm, int b0) {
    __shared__ float t[64][67];
    int bl = blockIdx.z, b = b0 + bl;
    int c0 = blockIdx.y * 64, p0 = blockIdx.x * 64;
    int tid = threadIdx.x;
    int cl = tid >> 4;
    int pc = tid & 15;
    int p = p0 + pc * 4;
#pragma unroll
    for (int q = 0; q < 4; q++) {
        int c_local = q * 16 + cl;
        const float* src = ev + ((size_t)b * C_ + c0 + c_local) * HW_;
        float4 v = make_float4(0.f, 0.f, 0.f, 0.f);
        if (p + 3 < HW_) v = *(const float4*)(src + p);
        else if (p < HW_) { for (int j = 0; j < 4; j++) if (p + j < HW_) ((float*)&v)[j] = src[p + j]; }
        if (doevm) {
            float rs = v.x + v.y + v.z + v.w;
            rs += __shfl_xor(rs, 1, 16);
            rs += __shfl_xor(rs, 2, 16);
            rs += __shfl_xor(rs, 4, 16);
            rs += __shfl_xor(rs, 8, 16);
            if (pc == 0) atomicAdd(&evsum[b * C_ + c0 + c_local], rs * (1.0f / HW_));
        }
        t[c_local][pc * 4 + 0] = v.x; t[c_local][pc * 4 + 1] = v.y;
        t[c_local][pc * 4 + 2] = v.z; t[c_local][pc * 4 + 3] = v.w;
    }
    __syncthreads();
    int r = tid >> 3;   // 0..31 p-row
    int j = tid & 7;    // c-chunk of 8
#pragma unroll
    for (int q = 0; q < 2; q++) {
        int prow = p0 + r + q * 32;
        if (prow < HW_) {
            uc8 o;
#pragma unroll
            for (int k = 0; k < 8; k++) o[k] = f2fp8(t[j * 8 + k][r + q * 32]);
            *(uc8*)(evT + ((size_t)bl * HW_ + prow) * C_ + c0 + j * 8) = o;
        }
    }
}

// ---------------------------------------------------------------- MFMA GEMM (fp8): [Wv;U](704x512) @ evT^T (512 x nb*784 flat)
// n-tiles of 128 span b-boundaries; zero padding waste in N.
__global__ __launch_bounds__(256, 4)
void k_gemm(const unsigned char* __restrict__ Abf, const unsigned char* __restrict__ evT,
            float* __restrict__ n2, unsigned short* __restrict__ Tb, int ntiles) {
    __shared__ unsigned char As[2][4096];   // [128][32] fp8
    __shared__ unsigned char Bs[2][4096];

    int id = blockIdx.x;
    int xcd = id & 7, slot = id >> 3;
    int S = (ntiles + 7) >> 3;
    int w = xcd * S + slot;
    if (w >= ntiles) return;
    int nt = w / 6, ot = w % 6;
    int o0 = ot * 128, n0 = nt * 128;

    int tid = threadIdx.x;
    int wid = tid >> 6, lane = tid & 63;
    int wy = wid >> 1, wx = wid & 1;
    int l15 = lane & 15, l4 = lane >> 4;

    const unsigned char* Ag = Abf + ((size_t)o0 + (tid >> 1)) * C_ + (tid & 1) * 16;
    const unsigned char* Bg = evT + ((size_t)n0 + (tid >> 1)) * C_ + (tid & 1) * 16;
    int lds_off = tid * 16;

    f4 acc[4][4] = {};
    int cur = 0;

#define STAGE(buf, k0) do { \
    gld16(Ag + (k0), &As[buf][0] + lds_off); \
    gld16(Bg + (k0), &Bs[buf][0] + lds_off); \
} while (0)

    STAGE(0, 0);
    __syncthreads();
    for (int t = 0; t < 16; ++t) {
        if (t < 15) STAGE(cur ^ 1, (t + 1) * 32);
        const long* Ar = (const long*)&As[cur][0];
        const long* Br = (const long*)&Bs[cur][0];
        long a[4], b[4];
#pragma unroll
        for (int mi = 0; mi < 4; mi++) a[mi] = Ar[(wy * 64 + mi * 16 + l15) * 4 + l4];
#pragma unroll
        for (int ni = 0; ni < 4; ni++) b[ni] = Br[(wx * 64 + ni * 16 + l15) * 4 + l4];
#pragma unroll
        for (int mi = 0; mi < 4; mi++)
#pragma unroll
            for (int ni = 0; ni < 4; ni++)
                acc[mi][ni] = __builtin_amdgcn_mfma_f32_16x16x32_fp8_fp8(a[mi], b[ni], acc[mi][ni], 0, 0, 0);
        __syncthreads();
        cur ^= 1;
    }
#undef STAGE

    if (ot < 4) {
        float* red = (float*)&As[0][0];
#pragma unroll
        for (int ni = 0; ni < 4; ni++) {
            float s = 0.f;
#pragma unroll
            for (int mi = 0; mi < 4; mi++)
#pragma unroll
                for (int r = 0; r < 4; r++) { float x = acc[mi][ni][r]; s = fmaf(x, x, s); }
            red[(wy * 4 + l4) * 128 + wx * 64 + ni * 16 + l15] = s;
        }
        __syncthreads();
        if (tid < 128) {
            float s = 0.f;
#pragma unroll
            for (int q = 0; q < 8; q++) s += red[q * 128 + tid];
            atomicAdd(&n2[n0 + tid], s);
        }
    } else {
        int dbase = o0 - 512 + wy * 64;
        unsigned blv[4]; int pv[4];
#pragma unroll
        for (int ni = 0; ni < 4; ni++) {
            unsigned nn = (unsigned)(n0 + wx * 64 + ni * 16 + l15);
            blv[ni] = nn / 784u;
            pv[ni]  = (int)(nn - blv[ni] * 784u);
        }
#pragma unroll
        for (int mi = 0; mi < 4; mi++)
#pragma unroll
            for (int r = 0; r < 4; r++) {
                int dd = dbase + mi * 16 + l4 * 4 + r;
                if (dd < B_) {
#pragma unroll
                    for (int ni = 0; ni < 4; ni++)
                        Tb[((size_t)blv[ni] * B_ + dd) * HW_ + pv[ni]] = f2bf(acc[mi][ni][r]);
                }
            }
    }
}

// ---------------------------------------------------------------- invn[i] = 1/max(sqrt(n2),1e-12)
__global__ void k_invn(const float* __restrict__ n2, float* __restrict__ invn, int n) {
    int i = blockIdx.x * 256 + threadIdx.x;
    if (i >= n) return;
    invn[i] = 1.0f / fmaxf(sqrtf(n2[i]), 1e-12f);
}

// ---------------------------------------------------------------- pool: wave per (b,d); dual interleaved bisection
__global__ __launch_bounds__(256)
void k_pool(const unsigned short* __restrict__ T, const float* __restrict__ invn,
            float* __restrict__ SP, float* __restrict__ SN, int b0) {
    int tid = threadIdx.x;
    int wv = tid >> 6, lane = tid & 63;
    int d = blockIdx.x * 4 + wv;
    int bl = blockIdx.y, b = b0 + bl;
    const unsigned short* Trow = T + ((size_t)b * B_ + d) * HW_;
    const float* nrow = invn + (size_t)b * HW_;
    float sv[13];
#pragma unroll
    for (int i = 0; i < 12; i++) {
        int p = lane + i * 64;
        sv[i] = bf2f(Trow[p]) * nrow[p];
    }
    {
        int p = lane + 768;
        sv[12] = (p < HW_) ? bf2f(Trow[p]) * nrow[p] : __uint_as_float(0x7FC00000u);
    }
    float vmax = -1e30f, vmin = 1e30f;
#pragma unroll
    for (int i = 0; i < 13; i++) { vmax = fmaxf(vmax, sv[i]); vmin = fminf(vmin, sv[i]); }
#pragma unroll
    for (int off = 32; off > 0; off >>= 1) {
        vmax = fmaxf(vmax, __shfl_xor(vmax, off, 64));
        vmin = fminf(vmin, __shfl_xor(vmin, off, 64));
    }
    float lo1 = vmin, hi1 = vmax, lo2 = vmin, hi2 = vmax;
    for (int it = 0; it < 13; ++it) {
        float m1 = 0.5f * (lo1 + hi1), m2 = 0.5f * (lo2 + hi2);
        int c1 = 0, c2 = 0;
#pragma unroll
        for (int i = 0; i < 13; i++) {
            c1 += __popcll(__ballot(sv[i] >= m1));
            c2 += __popcll(__ballot(sv[i] <= m2));
        }
        if (c1 >= TPK) lo1 = m1; else hi1 = m1;
        if (c2 >= TPK) hi2 = m2; else lo2 = m2;
    }
    float thrp = lo1, thrn = hi2;
    const float its = 1.0f / 0.03f;
    float spn = 0.f, spd = 0.f, snn = 0.f, snd = 0.f;
#pragma unroll
    for (int i = 0; i < 13; i++) {
        if (i == 12 && lane >= 16) continue;
        float s = sv[i];
        float mp = sigf((s - thrp) * its);
        float mn = sigf(-(s - thrn) * its);
        spn += s * mp; spd += mp;
        snn += s * mn; snd += mn;
    }
    for (int off = 32; off > 0; off >>= 1) {
        spn += __shfl_down(spn, off, 64);
        spd += __shfl_down(spd, off, 64);
        snn += __shfl_down(snn, off, 64);
        snd += __shfl_down(snd, off, 64);
    }
    if (lane == 0) {
        SP[b * B_ + d] = spn / spd;
        SN[b * B_ + d] = snn / snd;
    }
}

// ---------------------------------------------------------------- CE losses
__global__ void k_loss12(const float* __restrict__ SP, const float* __restrict__ SN,
                         float* __restrict__ acc) {
    __shared__ float red[128];
    int i = blockIdx.x, tid = threadIdx.x;
    const float itc = 1.0f / 0.07f;
    for (int phase = 0; phase < 2; phase++) {
        float mx = -INFINITY;
        for (int j = tid; j < 2 * B_; j += 128) {
            float v;
            if (phase == 0) v = (j < B_ ? SP[i * B_ + j] : SN[i * B_ + (j - B_)]);
            else            v = (j < B_ ? SP[j * B_ + i] : SN[(j - B_) * B_ + i]);
            mx = fmaxf(mx, v * itc);
        }
        red[tid] = mx; __syncthreads();
        for (int s = 64; s > 0; s >>= 1) { if (tid < s) red[tid] = fmaxf(red[tid], red[tid + s]); __syncthreads(); }
        mx = red[0]; __syncthreads();
        float se = 0.f;
        for (int j = tid; j < 2 * B_; j += 128) {
            float v;
            if (phase == 0) v = (j < B_ ? SP[i * B_ + j] : SN[i * B_ + (j - B_)]);
            else            v = (j < B_ ? SP[j * B_ + i] : SN[(j - B_) * B_ + i]);
            se += __expf(v * itc - mx);
        }
        red[tid] = se; __syncthreads();
        for (int s = 64; s > 0; s >>= 1) { if (tid < s) red[tid] += red[tid + s]; __syncthreads(); }
        if (tid == 0) {
            float lse = logf(red[0]) + mx;
            atomicAdd(&acc[phase], lse - SP[i * B_ + i] * itc);
        }
        __syncthreads();
    }
}

// ---------------------------------------------------------------- fused distance matrix + final (last block)
__global__ __launch_bounds__(256)
void k_distfin(const float* __restrict__ iv, const float* __restrict__ ivn,
               const float* __restrict__ fa, const float* __restrict__ acc,
               float* __restrict__ rowsum, float* __restrict__ colsum,
               int* __restrict__ cnt, float* __restrict__ out) {
    __shared__ float Ai[16][68], An[16][68], Bf[16][68], Bn[16][68];
    __shared__ float rred[64][17], cred[64][17];
    __shared__ float fr[256];
    __shared__ int lastf;
    int i0 = blockIdx.y * 64, j0 = blockIdx.x * 64;
    int tid = threadIdx.x;
    int tx = tid & 15, ty = tid >> 4;
    int r = tid >> 2, c4 = tid & 3;
    float accD[4][4], accV[4][4];
#pragma unroll
    for (int i = 0; i < 4; i++)
#pragma unroll
        for (int j = 0; j < 4; j++) { accD[i][j] = 0.f; accV[i][j] = 0.f; }

    for (int k0 = 0; k0 < C_; k0 += 16) {
        float4 v;
        v = *(const float4*)(iv + (size_t)(i0 + r) * C_ + k0 + c4 * 4);
        Ai[c4*4+0][r]=v.x; Ai[c4*4+1][r]=v.y; Ai[c4*4+2][r]=v.z; Ai[c4*4+3][r]=v.w;
        v = *(const float4*)(ivn + (size_t)(i0 + r) * C_ + k0 + c4 * 4);
        An[c4*4+0][r]=v.x; An[c4*4+1][r]=v.y; An[c4*4+2][r]=v.z; An[c4*4+3][r]=v.w;
        v = *(const float4*)(fa + (size_t)(j0 + r) * C_ + k0 + c4 * 4);
        Bf[c4*4+0][r]=v.x; Bf[c4*4+1][r]=v.y; Bf[c4*4+2][r]=v.z; Bf[c4*4+3][r]=v.w;
        v = *(const float4*)(ivn + (size_t)(j0 + r) * C_ + k0 + c4 * 4);
        Bn[c4*4+0][r]=v.x; Bn[c4*4+1][r]=v.y; Bn[c4*4+2][r]=v.z; Bn[c4*4+3][r]=v.w;
        __syncthreads();
#pragma unroll
        for (int kk = 0; kk < 16; kk++) {
            float ai[4], an[4];
#pragma unroll
            for (int i = 0; i < 4; i++) { ai[i] = Ai[kk][ty*4+i]; an[i] = An[kk][ty*4+i]; }
            float4 bf = *(const float4*)&Bf[kk][tx*4];
            float4 bn = *(const float4*)&Bn[kk][tx*4];
#pragma unroll
            for (int i = 0; i < 4; i++) {
                float d0 = ai[i] - bf.x + 1e-6f; accD[i][0] = fmaf(d0, d0, accD[i][0]);
                float d1 = ai[i] - bf.y + 1e-6f; accD[i][1] = fmaf(d1, d1, accD[i][1]);
                float d2 = ai[i] - bf.z + 1e-6f; accD[i][2] = fmaf(d2, d2, accD[i][2]);
                float d3 = ai[i] - bf.w + 1e-6f; accD[i][3] = fmaf(d3, d3, accD[i][3]);
                accV[i][0] = fmaf(an[i], bn.x, accV[i][0]);
                accV[i][1] = fmaf(an[i], bn.y, accV[i][1]);
                accV[i][2] = fmaf(an[i], bn.z, accV[i][2]);
                accV[i][3] = fmaf(an[i], bn.w, accV[i][3]);
            }
        }
        __syncthreads();
    }
    float rp[4] = {0.f, 0.f, 0.f, 0.f};
    float cp[4] = {0.f, 0.f, 0.f, 0.f};
#pragma unroll
    for (int i = 0; i < 4; i++)
#pragma unroll
        for (int j = 0; j < 4; j++) {
            int gi = i0 + ty * 4 + i, gj = j0 + tx * 4 + j;
            float val = (gi == gj) ? accD[i][j] : accD[i][j] * accV[i][j] * (1.0f / 191.0f);
            rp[i] += val; cp[j] += val;
        }
#pragma unroll
    for (int i = 0; i < 4; i++) rred[ty * 4 + i][tx] = rp[i];
#pragma unroll
    for (int j = 0; j < 4; j++) cred[tx * 4 + j][ty] = cp[j];
    __syncthreads();
    if (tid < 64) {
        float s = 0.f;
#pragma unroll
        for (int q = 0; q < 16; q++) s += rred[tid][q];
        atomicAdd(&rowsum[i0 + tid], s);
    } else if (tid < 128) {
        int t = tid - 64;
        float s = 0.f;
#pragma unroll
        for (int q = 0; q < 16; q++) s += cred[t][q];
        atomicAdd(&colsum[j0 + t], s);
    }
    __threadfence();
    __syncthreads();
    if (tid == 0) lastf = (atomicAdd(cnt, 1) == 8);
    __syncthreads();
    if (lastf) {
        __threadfence();
        float v3 = (tid < B_) ? fmaxf(rowsum[tid] + 0.6f, 0.f) : 0.f;
        float v4 = (tid < B_) ? fmaxf(colsum[tid] + 0.6f, 0.f) : 0.f;
        fr[tid] = v3; __syncthreads();
        for (int s = 128; s > 0; s >>= 1) { if (tid < s) fr[tid] += fr[tid + s]; __syncthreads(); }
        float l3 = fr[0] / B_;
        __syncthreads();
        fr[tid] = v4; __syncthreads();
        for (int s = 128; s > 0; s >>= 1) { if (tid < s) fr[tid] += fr[tid + s]; __syncthreads(); }
        float l4 = fr[0] / B_;
        if (tid == 0) {
            out[0] = 0.5f * (acc[0] + acc[1]) / B_;
            out[1] = 0.5f * (l3 + l4);
        }
    }
}

extern "C" void kernel_launch(void* const* d_in, const int* in_sizes, int n_in,
                              void* d_out, int out_size, void* d_ws, size_t ws_size,
                              hipStream_t stream) {
    const float* ev  = (const float*)d_in[0];
    const float* ea  = (const float*)d_in[1];
    const float* Wv  = (const float*)d_in[2];
    const float* Wa1 = (const float*)d_in[3];
    const float* Wa2 = (const float*)d_in[4];
    float* out = (float*)d_out;
    float* ws  = (float*)d_ws;

    size_t off = 0;
    // contiguous zero block: evmean..fa, n2, acc/rowsum/colsum/cnt
    float* evmean  = ws + off; off += B_ * C_;
    float* ind_vec = ws + off; off += B_ * C_;
    float* Hb      = ws + off; off += B_ * C_;
    float* fa      = ws + off; off += B_ * C_;
    float* n2      = ws + off; off += NTOT;
    float* accb    = ws + off;
    float* rowsum  = accb + 16;
    float* colsum  = rowsum + B_;
    int*   cntp    = (int*)(colsum + B_);
    off += 16 + B_ + B_ + 16;
    size_t zero_count = off;
    float* iv_norm = ws + off; off += B_ * C_;
    float* invn    = ws + off; off += NTOT;
    float* SPb     = ws + off; off += B_ * B_;
    float* SNb     = ws + off; off += B_ * B_;
    unsigned char* Abf = (unsigned char*)(ws + off); off += 768 * C_ / 4;   // fp8 bytes

    // per-b: evT fp8 flat (HW_*C_ bytes) + Tb bf16 (B_*HW_ elems)
    size_t perB_f = (size_t)HW_ * C_ / 4 + (size_t)B_ * HW_ / 2;
    size_t avail  = ws_size / 4 > off ? ws_size / 4 - off : 0;
    int chunk = (int)(avail / perB_f);
    chunk &= ~7;                    // multiple of 8 so nb*784 is a multiple of 128
    if (chunk > B_) chunk = B_;
    if (chunk < 8) chunk = 8;
    unsigned char* evT = (unsigned char*)(ws + off);
    unsigned short* Tb = (unsigned short*)(evT + (size_t)chunk * HW_ * C_);

    hipMemsetAsync(ws, 0, zero_count * sizeof(float), stream);

    k_prepA<<<576, 256, 0, stream>>>(Wv, Abf);

    if (chunk >= B_) {
        dim3 gt(13, C_ / 64, B_);
        k_transpose64<<<gt, 256, 0, stream>>>(ev, evT, evmean, 1, 0);
    } else {
        k_evmean<<<B_ * C_ / 4, 256, 0, stream>>>(ev, evmean);
    }

    // audio chain (split-K for occupancy)
    k32<0, 0, 4><<<dim3(8, 3, 4), 256, 0, stream>>>(ea, Wa1, Hb, B_, C_, 2048);
    k32<0, 1, 2><<<dim3(8, 3, 2), 256, 0, stream>>>(Hb, Wa2, fa, B_, C_, C_);

    // visual chain
    k32<0, 0, 2><<<dim3(8, 3, 2), 256, 0, stream>>>(evmean, Wv, ind_vec, B_, C_, C_);
    k_rownorm<<<B_, 64, 0, stream>>>(ind_vec, iv_norm);
    k_Ufp8<<<dim3(8, 3), 256, 0, stream>>>(iv_norm, Wv, Abf);

    if (chunk >= B_) {
        int ntiles = (NTOT / 128) * 6;            // 7056 = 8*882, no pad
        int S = (ntiles + 7) >> 3;
        k_gemm<<<8 * S, 256, 0, stream>>>(Abf, evT, n2, Tb, ntiles);
        k_invn<<<(NTOT + 255) / 256, 256, 0, stream>>>(n2, invn, NTOT);
        dim3 gp(B_ / 4, B_);
        k_pool<<<gp, 256, 0, stream>>>(Tb, invn, SPb, SNb, 0);
    } else {
        for (int b0 = 0; b0 < B_; b0 += chunk) {
            int nb = (B_ - b0 < chunk) ? (B_ - b0) : chunk;
            dim3 gt(13, C_ / 64, nb);
            k_transpose64<<<gt, 256, 0, stream>>>(ev, evT, evmean, 0, b0);
            int ntiles = (nb * HW_ / 128) * 6;
            int S = (ntiles + 7) >> 3;
            k_gemm<<<8 * S, 256, 0, stream>>>(Abf, evT, n2 + (size_t)b0 * HW_, Tb, ntiles);
            int n = nb * HW_;
            k_invn<<<(n + 255) / 256, 256, 0, stream>>>(n2 + (size_t)b0 * HW_,
                                                        invn + (size_t)b0 * HW_, n);
            dim3 gp(B_ / 4, nb);
            k_pool<<<gp, 256, 0, stream>>>(Tb - (size_t)b0 * B_ * HW_, invn, SPb, SNb, b0);
        }
    }

    k_loss12<<<B_, 128, 0, stream>>>(SPb, SNb, accb);
    dim3 gd(B_ / 64, B_ / 64);
    k_distfin<<<gd, 256, 0, stream>>>(ind_vec, iv_norm, fa, accb, rowsum, colsum, cntp, out);
}

// Round 10
// 443.902 us; speedup vs baseline: 1.3077x; 1.0912x over previous
//
#include <hip/hip_runtime.h>
#include <hip/hip_fp8.h>
#include <math.h>

#define B_   192
#define C_   512
#define HW_  784
#define TPK  23          // int(784*0.03)
#define NTOT (B_ * HW_)  // 150528 = 1176 * 128 exactly
#define SCL  0x7F7F7F7F  // E8M0 unit scales (127 -> 2^0)

typedef __attribute__((ext_vector_type(4))) float f4;
typedef __attribute__((ext_vector_type(16))) float f16v;
typedef __attribute__((ext_vector_type(8))) int i8i;
typedef __attribute__((ext_vector_type(4))) unsigned int u4i;
typedef __attribute__((ext_vector_type(8))) unsigned char uc8;

__device__ __forceinline__ float sigf(float x) {
    return 1.0f / (1.0f + __expf(-x));
}
__device__ __forceinline__ unsigned short f2bf(float f) {
    unsigned u = __float_as_uint(f);
    unsigned r = u + 0x7FFFu + ((u >> 16) & 1u);
    return (unsigned short)(r >> 16);
}
__device__ __forceinline__ float bf2f(unsigned short u) {
    return __uint_as_float(((unsigned)u) << 16);
}
__device__ __forceinline__ unsigned char f2fp8(float x) {
    __hip_fp8_e4m3 t(x);                 // OCP e4m3fn, RNE
    return (unsigned char)t.__x;
}
__device__ __forceinline__ void gld16(const void* g, void* l) {
    __builtin_amdgcn_global_load_lds((const __attribute__((address_space(1))) unsigned int*)g,
                                     (__attribute__((address_space(3))) unsigned int*)l, 16, 0, 0);
}
__device__ __forceinline__ i8i frag32(const unsigned char* base, int c0, int c1) {
    u4i lo = *(const u4i*)(base + c0);
    u4i hi = *(const u4i*)(base + c1);
    i8i r;
    r[0] = (int)lo[0]; r[1] = (int)lo[1]; r[2] = (int)lo[2]; r[3] = (int)lo[3];
    r[4] = (int)hi[0]; r[5] = (int)hi[1]; r[6] = (int)hi[2]; r[7] = (int)hi[3];
    return r;
}

// ---------------------------------------------------------------- evmean (fallback only)
__global__ void k_evmean(const float* __restrict__ ev, float* __restrict__ evmean) {
    int row  = blockIdx.x * 4 + (threadIdx.x >> 6);
    int lane = threadIdx.x & 63;
    const float4* s4 = (const float4*)(ev + (size_t)row * HW_);
    float s = 0.f;
    for (int i = lane; i < HW_ / 4; i += 64) {
        float4 v = s4[i];
        s += v.x + v.y + v.z + v.w;
    }
    for (int off = 32; off > 0; off >>= 1) s += __shfl_down(s, off, 64);
    if (lane == 0) evmean[row] = s * (1.0f / HW_);
}

// ---------------------------------------------------------------- tiled fp32 GEMM w/ split-K
template<int BKN, int RELUA, int SPLITK>
__global__ __launch_bounds__(256)
void k32(const float* __restrict__ A, const float* __restrict__ B,
         float* __restrict__ C, int M, int N, int K) {
    __shared__ float As[16][68];
    __shared__ float Bs[16][68];
    int m0 = blockIdx.y * 64, n0 = blockIdx.x * 64;
    int kslice = K / SPLITK;
    int kbeg = blockIdx.z * kslice;
    int tid = threadIdx.x;
    int tx = tid & 15, ty = tid >> 4;
    int r = tid >> 2, c4 = tid & 3;

    float acc[4][4];
#pragma unroll
    for (int i = 0; i < 4; i++)
#pragma unroll
        for (int j = 0; j < 4; j++) acc[i][j] = 0.f;

    for (int k0 = kbeg; k0 < kbeg + kslice; k0 += 16) {
        float4 av = *(const float4*)(A + (size_t)(m0 + r) * K + k0 + c4 * 4);
        if (RELUA) {
            av.x = fmaxf(av.x, 0.f); av.y = fmaxf(av.y, 0.f);
            av.z = fmaxf(av.z, 0.f); av.w = fmaxf(av.w, 0.f);
        }
        As[c4 * 4 + 0][r] = av.x; As[c4 * 4 + 1][r] = av.y;
        As[c4 * 4 + 2][r] = av.z; As[c4 * 4 + 3][r] = av.w;
        if (BKN == 0) {
            float4 bv = *(const float4*)(B + (size_t)(n0 + r) * K + k0 + c4 * 4);
            Bs[c4 * 4 + 0][r] = bv.x; Bs[c4 * 4 + 1][r] = bv.y;
            Bs[c4 * 4 + 2][r] = bv.z; Bs[c4 * 4 + 3][r] = bv.w;
        } else {
            float4 bv = *(const float4*)(B + (size_t)(k0 + ty) * N + n0 + tx * 4);
            Bs[ty][tx * 4 + 0] = bv.x; Bs[ty][tx * 4 + 1] = bv.y;
            Bs[ty][tx * 4 + 2] = bv.z; Bs[ty][tx * 4 + 3] = bv.w;
        }
        __syncthreads();
#pragma unroll
        for (int kk = 0; kk < 16; kk++) {
            float a_[4];
#pragma unroll
            for (int i = 0; i < 4; i++) a_[i] = As[kk][ty * 4 + i];
            float4 bb = *(const float4*)&Bs[kk][tx * 4];
#pragma unroll
            for (int i = 0; i < 4; i++) {
                acc[i][0] = fmaf(a_[i], bb.x, acc[i][0]);
                acc[i][1] = fmaf(a_[i], bb.y, acc[i][1]);
                acc[i][2] = fmaf(a_[i], bb.z, acc[i][2]);
                acc[i][3] = fmaf(a_[i], bb.w, acc[i][3]);
            }
        }
        __syncthreads();
    }
#pragma unroll
    for (int i = 0; i < 4; i++) {
        if (SPLITK > 1) {
            float* row = C + (size_t)(m0 + ty * 4 + i) * N + n0 + tx * 4;
#pragma unroll
            for (int j = 0; j < 4; j++) atomicAdd(&row[j], acc[i][j]);
        } else {
            *(float4*)(C + (size_t)(m0 + ty * 4 + i) * N + n0 + tx * 4) =
                make_float4(acc[i][0], acc[i][1], acc[i][2], acc[i][3]);
        }
    }
}

// ---------------------------------------------------------------- iv_norm = l2norm(ind_vec) per row
__global__ void k_rownorm(const float* __restrict__ iv, float* __restrict__ ivn) {
    int b = blockIdx.x, lane = threadIdx.x;
    float v[8]; float s = 0.f;
#pragma unroll
    for (int k = 0; k < 8; k++) {
        v[k] = iv[(size_t)b * C_ + lane + 64 * k];
        s = fmaf(v[k], v[k], s);
    }
#pragma unroll
    for (int off = 32; off > 0; off >>= 1) s += __shfl_xor(s, off, 64);
    float rn = 1.0f / fmaxf(sqrtf(s), 1e-12f);
#pragma unroll
    for (int k = 0; k < 8; k++) ivn[(size_t)b * C_ + lane + 64 * k] = v[k] * rn;
}

// ---------------------------------------------------------------- Abf: rows 0..511 = fp8(Wv), 704..767 = 0; SWIZZLED
__global__ void k_prepA(const float* __restrict__ Wv, unsigned char* __restrict__ Abf) {
    int r = blockIdx.x, tid = threadIdx.x;
    int row = (r < 512) ? r : (192 + r);   // 512..575 -> 704..767 zero pad
    int swz = ((row >> 1) & 3) << 4;
    for (int i = 0; i < 2; i++) {
        int c = tid + i * 256;
        float v = (r < 512) ? Wv[(size_t)r * C_ + c] : 0.f;
        Abf[(size_t)row * C_ + (c ^ swz)] = f2fp8(v);
    }
}

// ---------------------------------------------------------------- U rows of Abf: fp8(ivn @ Wv), K=512; SWIZZLED
__global__ __launch_bounds__(256)
void k_Ufp8(const float* __restrict__ ivn, const float* __restrict__ Wv,
            unsigned char* __restrict__ Abf) {
    __shared__ float As[16][68];
    __shared__ float Bs[16][68];
    int m0 = blockIdx.y * 64, n0 = blockIdx.x * 64;
    int tid = threadIdx.x;
    int tx = tid & 15, ty = tid >> 4;
    int r = tid >> 2, c4 = tid & 3;
    float acc[4][4];
#pragma unroll
    for (int i = 0; i < 4; i++)
#pragma unroll
        for (int j = 0; j < 4; j++) acc[i][j] = 0.f;
    for (int k0 = 0; k0 < C_; k0 += 16) {
        float4 av = *(const float4*)(ivn + (size_t)(m0 + r) * C_ + k0 + c4 * 4);
        As[c4 * 4 + 0][r] = av.x; As[c4 * 4 + 1][r] = av.y;
        As[c4 * 4 + 2][r] = av.z; As[c4 * 4 + 3][r] = av.w;
        float4 bv = *(const float4*)(Wv + (size_t)(k0 + ty) * C_ + n0 + tx * 4);
        Bs[ty][tx * 4 + 0] = bv.x; Bs[ty][tx * 4 + 1] = bv.y;
        Bs[ty][tx * 4 + 2] = bv.z; Bs[ty][tx * 4 + 3] = bv.w;
        __syncthreads();
#pragma unroll
        for (int kk = 0; kk < 16; kk++) {
            float a_[4];
#pragma unroll
            for (int i = 0; i < 4; i++) a_[i] = As[kk][ty * 4 + i];
            float4 bb = *(const float4*)&Bs[kk][tx * 4];
#pragma unroll
            for (int i = 0; i < 4; i++) {
                acc[i][0] = fmaf(a_[i], bb.x, acc[i][0]);
                acc[i][1] = fmaf(a_[i], bb.y, acc[i][1]);
                acc[i][2] = fmaf(a_[i], bb.z, acc[i][2]);
                acc[i][3] = fmaf(a_[i], bb.w, acc[i][3]);
            }
        }
        __syncthreads();
    }
#pragma unroll
    for (int i = 0; i < 4; i++) {
        int orow = 512 + m0 + ty * 4 + i;
        int swz = ((orow >> 1) & 3) << 4;
        unsigned char* rowp = Abf + (size_t)orow * C_;
        int cphys = (n0 + tx * 4) ^ swz;
#pragma unroll
        for (int j = 0; j < 4; j++) rowp[cphys + j] = f2fp8(acc[i][j]);
    }
}

// ---------------------------------------------------------------- ev fp32 -> evT[n][c] fp8 flat; SWIZZLED
__global__ __launch_bounds__(256)
void k_transpose64(const float* __restrict__ ev, unsigned char* __restrict__ evT,
                   float* __restrict__ evsum, int doevm, int b0) {
    __shared__ float t[64][67];
    int bl = blockIdx.z, b = b0 + bl;
    int c0 = blockIdx.y * 64, p0 = blockIdx.x * 64;
    int tid = threadIdx.x;
    int cl = tid >> 4;
    int pc = tid & 15;
    int p = p0 + pc * 4;
#pragma unroll
    for (int q = 0; q < 4; q++) {
        int c_local = q * 16 + cl;
        const float* src = ev + ((size_t)b * C_ + c0 + c_local) * HW_;
        float4 v = make_float4(0.f, 0.f, 0.f, 0.f);
        if (p + 3 < HW_) v = *(const float4*)(src + p);
        else if (p < HW_) { for (int j = 0; j < 4; j++) if (p + j < HW_) ((float*)&v)[j] = src[p + j]; }
        if (doevm) {
            float rs = v.x + v.y + v.z + v.w;
            rs += __shfl_xor(rs, 1, 16);
            rs += __shfl_xor(rs, 2, 16);
            rs += __shfl_xor(rs, 4, 16);
            rs += __shfl_xor(rs, 8, 16);
            if (pc == 0) atomicAdd(&evsum[b * C_ + c0 + c_local], rs * (1.0f / HW_));
        }
        t[c_local][pc * 4 + 0] = v.x; t[c_local][pc * 4 + 1] = v.y;
        t[c_local][pc * 4 + 2] = v.z; t[c_local][pc * 4 + 3] = v.w;
    }
    __syncthreads();
    int r = tid >> 3;   // 0..31 p-row
    int j = tid & 7;    // c-chunk of 8
#pragma unroll
    for (int q = 0; q < 2; q++) {
        int prow = p0 + r + q * 32;
        if (prow < HW_) {
            size_t n = (size_t)bl * HW_ + prow;
            int swz = ((int)(n >> 1) & 3) << 4;
            uc8 o;
#pragma unroll
            for (int k = 0; k < 8; k++) o[k] = f2fp8(t[j * 8 + k][r + q * 32]);
            *(uc8*)(evT + n * C_ + c0 + ((j * 8) ^ swz)) = o;
        }
    }
}

// ---------------------------------------------------------------- MX-scaled MFMA GEMM: 32x32x64 f8f6f4, unit scales
// tiles 128x128, BK=64, 4 waves 2x2, wave 64x64 = 2x2 frags of 32x32
__global__ __launch_bounds__(256, 4)
void k_gemm(const unsigned char* __restrict__ Abf, const unsigned char* __restrict__ evT,
            float* __restrict__ n2, unsigned short* __restrict__ Tb, int ntiles) {
    __shared__ unsigned char As[2][8192];   // [128][64] fp8, swizzled
    __shared__ unsigned char Bs[2][8192];

    int id = blockIdx.x;
    int xcd = id & 7, slot = id >> 3;
    int S = (ntiles + 7) >> 3;
    int w = xcd * S + slot;
    if (w >= ntiles) return;
    int nt = w / 6, ot = w % 6;
    int o0 = ot * 128, n0 = nt * 128;

    int tid = threadIdx.x;
    int wid = tid >> 6, lane = tid & 63;
    int wy = wid >> 1, wx = wid & 1;
    int r31 = lane & 31, hi = lane >> 5;
    int swz = (r31 >> 1) & 3;
    int ch0 = ((2 * hi) ^ swz) * 16;
    int ch1 = ((2 * hi + 1) ^ swz) * 16;

    // staging: 128 rows x 64B per tile = 8KB = 256 thr x 2 gld16
    const unsigned char* Ag = Abf + ((size_t)o0 + (tid >> 2)) * C_ + (tid & 3) * 16;
    const unsigned char* Bg = evT + ((size_t)n0 + (tid >> 2)) * C_ + (tid & 3) * 16;
    int lds16 = tid * 16;

    f16v acc[2][2] = {};
    int cur = 0;

#define STAGE(buf, k0) do { \
    gld16(Ag + (k0),           &As[buf][0]    + lds16); \
    gld16(Ag + (k0) + 64 * C_, &As[buf][4096] + lds16); \
    gld16(Bg + (k0),           &Bs[buf][0]    + lds16); \
    gld16(Bg + (k0) + 64 * C_, &Bs[buf][4096] + lds16); \
} while (0)

    STAGE(0, 0);
    __syncthreads();
    for (int t = 0; t < 8; ++t) {
        if (t < 7) STAGE(cur ^ 1, (t + 1) * 64);
        const unsigned char* Ab = &As[cur][0];
        const unsigned char* Bb = &Bs[cur][0];
        i8i a[2], b[2];
#pragma unroll
        for (int mi = 0; mi < 2; mi++)
            a[mi] = frag32(Ab + (wy * 64 + mi * 32 + r31) * 64, ch0, ch1);
#pragma unroll
        for (int ni = 0; ni < 2; ni++)
            b[ni] = frag32(Bb + (wx * 64 + ni * 32 + r31) * 64, ch0, ch1);
#pragma unroll
        for (int mi = 0; mi < 2; mi++)
#pragma unroll
            for (int ni = 0; ni < 2; ni++)
                acc[mi][ni] = __builtin_amdgcn_mfma_scale_f32_32x32x64_f8f6f4(
                    a[mi], b[ni], acc[mi][ni], 0, 0, 0, SCL, 0, SCL);
        __syncthreads();
        cur ^= 1;
    }
#undef STAGE

    // C layout (32x32): col = lane&31, row = (reg&3) + 8*(reg>>2) + 4*hi
    if (ot < 4) {
        float* red = (float*)&As[0][0];
#pragma unroll
        for (int ni = 0; ni < 2; ni++) {
            float s = 0.f;
#pragma unroll
            for (int mi = 0; mi < 2; mi++)
#pragma unroll
                for (int r = 0; r < 16; r++) { float x = acc[mi][ni][r]; s = fmaf(x, x, s); }
            red[(wy * 2 + hi) * 128 + wx * 64 + ni * 32 + r31] = s;
        }
        __syncthreads();
        if (tid < 128) {
            float s = 0.f;
#pragma unroll
            for (int q = 0; q < 4; q++) s += red[q * 128 + tid];
            atomicAdd(&n2[n0 + tid], s);
        }
    } else {
        int dbase = o0 - 512 + wy * 64;
        unsigned blv[2]; int pv[2];
#pragma unroll
        for (int ni = 0; ni < 2; ni++) {
            unsigned nn = (unsigned)(n0 + wx * 64 + ni * 32 + r31);
            blv[ni] = nn / 784u;
            pv[ni]  = (int)(nn - blv[ni] * 784u);
        }
#pragma unroll
        for (int mi = 0; mi < 2; mi++)
#pragma unroll
            for (int r = 0; r < 16; r++) {
                int dd = dbase + mi * 32 + (r & 3) + 8 * (r >> 2) + 4 * hi;
                if (dd < B_) {
#pragma unroll
                    for (int ni = 0; ni < 2; ni++)
                        Tb[((size_t)blv[ni] * B_ + dd) * HW_ + pv[ni]] = f2bf(acc[mi][ni][r]);
                }
            }
    }
}

// ---------------------------------------------------------------- invn[i] = 1/max(sqrt(n2),1e-12)
__global__ void k_invn(const float* __restrict__ n2, float* __restrict__ invn, int n) {
    int i = blockIdx.x * 256 + threadIdx.x;
    if (i >= n) return;
    invn[i] = 1.0f / fmaxf(sqrtf(n2[i]), 1e-12f);
}

// ---------------------------------------------------------------- pool: wave per (b,d); dual interleaved bisection
__global__ __launch_bounds__(256)
void k_pool(const unsigned short* __restrict__ T, const float* __restrict__ invn,
            float* __restrict__ SP, float* __restrict__ SN, int b0) {
    int tid = threadIdx.x;
    int wv = tid >> 6, lane = tid & 63;
    int d = blockIdx.x * 4 + wv;
    int bl = blockIdx.y, b = b0 + bl;
    const unsigned short* Trow = T + ((size_t)b * B_ + d) * HW_;
    const float* nrow = invn + (size_t)b * HW_;
    float sv[13];
#pragma unroll
    for (int i = 0; i < 12; i++) {
        int p = lane + i * 64;
        sv[i] = bf2f(Trow[p]) * nrow[p];
    }
    {
        int p = lane + 768;
        sv[12] = (p < HW_) ? bf2f(Trow[p]) * nrow[p] : __uint_as_float(0x7FC00000u);
    }
    float vmax = -1e30f, vmin = 1e30f;
#pragma unroll
    for (int i = 0; i < 13; i++) { vmax = fmaxf(vmax, sv[i]); vmin = fminf(vmin, sv[i]); }
#pragma unroll
    for (int off = 32; off > 0; off >>= 1) {
        vmax = fmaxf(vmax, __shfl_xor(vmax, off, 64));
        vmin = fminf(vmin, __shfl_xor(vmin, off, 64));
    }
    float lo1 = vmin, hi1 = vmax, lo2 = vmin, hi2 = vmax;
    for (int it = 0; it < 13; ++it) {
        float m1 = 0.5f * (lo1 + hi1), m2 = 0.5f * (lo2 + hi2);
        int c1 = 0, c2 = 0;
#pragma unroll
        for (int i = 0; i < 13; i++) {
            c1 += __popcll(__ballot(sv[i] >= m1));
            c2 += __popcll(__ballot(sv[i] <= m2));
        }
        if (c1 >= TPK) lo1 = m1; else hi1 = m1;
        if (c2 >= TPK) hi2 = m2; else lo2 = m2;
    }
    float thrp = lo1, thrn = hi2;
    const float its = 1.0f / 0.03f;
    float spn = 0.f, spd = 0.f, snn = 0.f, snd = 0.f;
#pragma unroll
    for (int i = 0; i < 13; i++) {
        if (i == 12 && lane >= 16) continue;
        float s = sv[i];
        float mp = sigf((s - thrp) * its);
        float mn = sigf(-(s - thrn) * its);
        spn += s * mp; spd += mp;
        snn += s * mn; snd += mn;
    }
    for (int off = 32; off > 0; off >>= 1) {
        spn += __shfl_down(spn, off, 64);
        spd += __shfl_down(spd, off, 64);
        snn += __shfl_down(snn, off, 64);
        snd += __shfl_down(snd, off, 64);
    }
    if (lane == 0) {
        SP[b * B_ + d] = spn / spd;
        SN[b * B_ + d] = snn / snd;
    }
}

// ---------------------------------------------------------------- CE losses
__global__ void k_loss12(const float* __restrict__ SP, const float* __restrict__ SN,
                         float* __restrict__ acc) {
    __shared__ float red[128];
    int i = blockIdx.x, tid = threadIdx.x;
    const float itc = 1.0f / 0.07f;
    for (int phase = 0; phase < 2; phase++) {
        float mx = -INFINITY;
        for (int j = tid; j < 2 * B_; j += 128) {
            float v;
            if (phase == 0) v = (j < B_ ? SP[i * B_ + j] : SN[i * B_ + (j - B_)]);
            else            v = (j < B_ ? SP[j * B_ + i] : SN[(j - B_) * B_ + i]);
            mx = fmaxf(mx, v * itc);
        }
        red[tid] = mx; __syncthreads();
        for (int s = 64; s > 0; s >>= 1) { if (tid < s) red[tid] = fmaxf(red[tid], red[tid + s]); __syncthreads(); }
        mx = red[0]; __syncthreads();
        float se = 0.f;
        for (int j = tid; j < 2 * B_; j += 128) {
            float v;
            if (phase == 0) v = (j < B_ ? SP[i * B_ + j] : SN[i * B_ + (j - B_)]);
            else            v = (j < B_ ? SP[j * B_ + i] : SN[(j - B_) * B_ + i]);
            se += __expf(v * itc - mx);
        }
        red[tid] = se; __syncthreads();
        for (int s = 64; s > 0; s >>= 1) { if (tid < s) red[tid] += red[tid + s]; __syncthreads(); }
        if (tid == 0) {
            float lse = logf(red[0]) + mx;
            atomicAdd(&acc[phase], lse - SP[i * B_ + i] * itc);
        }
        __syncthreads();
    }
}

// ---------------------------------------------------------------- fused distance matrix + final (last block)
__global__ __launch_bounds__(256)
void k_distfin(const float* __restrict__ iv, const float* __restrict__ ivn,
               const float* __restrict__ fa, const float* __restrict__ acc,
               float* __restrict__ rowsum, float* __restrict__ colsum,
               int* __restrict__ cnt, float* __restrict__ out) {
    __shared__ float Ai[16][68], An[16][68], Bf[16][68], Bn[16][68];
    __shared__ float rred[64][17], cred[64][17];
    __shared__ float fr[256];
    __shared__ int lastf;
    int i0 = blockIdx.y * 64, j0 = blockIdx.x * 64;
    int tid = threadIdx.x;
    int tx = tid & 15, ty = tid >> 4;
    int r = tid >> 2, c4 = tid & 3;
    float accD[4][4], accV[4][4];
#pragma unroll
    for (int i = 0; i < 4; i++)
#pragma unroll
        for (int j = 0; j < 4; j++) { accD[i][j] = 0.f; accV[i][j] = 0.f; }

    for (int k0 = 0; k0 < C_; k0 += 16) {
        float4 v;
        v = *(const float4*)(iv + (size_t)(i0 + r) * C_ + k0 + c4 * 4);
        Ai[c4*4+0][r]=v.x; Ai[c4*4+1][r]=v.y; Ai[c4*4+2][r]=v.z; Ai[c4*4+3][r]=v.w;
        v = *(const float4*)(ivn + (size_t)(i0 + r) * C_ + k0 + c4 * 4);
        An[c4*4+0][r]=v.x; An[c4*4+1][r]=v.y; An[c4*4+2][r]=v.z; An[c4*4+3][r]=v.w;
        v = *(const float4*)(fa + (size_t)(j0 + r) * C_ + k0 + c4 * 4);
        Bf[c4*4+0][r]=v.x; Bf[c4*4+1][r]=v.y; Bf[c4*4+2][r]=v.z; Bf[c4*4+3][r]=v.w;
        v = *(const float4*)(ivn + (size_t)(j0 + r) * C_ + k0 + c4 * 4);
        Bn[c4*4+0][r]=v.x; Bn[c4*4+1][r]=v.y; Bn[c4*4+2][r]=v.z; Bn[c4*4+3][r]=v.w;
        __syncthreads();
#pragma unroll
        for (int kk = 0; kk < 16; kk++) {
            float ai[4], an[4];
#pragma unroll
            for (int i = 0; i < 4; i++) { ai[i] = Ai[kk][ty*4+i]; an[i] = An[kk][ty*4+i]; }
            float4 bf = *(const float4*)&Bf[kk][tx*4];
            float4 bn = *(const float4*)&Bn[kk][tx*4];
#pragma unroll
            for (int i = 0; i < 4; i++) {
                float d0 = ai[i] - bf.x + 1e-6f; accD[i][0] = fmaf(d0, d0, accD[i][0]);
                float d1 = ai[i] - bf.y + 1e-6f; accD[i][1] = fmaf(d1, d1, accD[i][1]);
                float d2 = ai[i] - bf.z + 1e-6f; accD[i][2] = fmaf(d2, d2, accD[i][2]);
                float d3 = ai[i] - bf.w + 1e-6f; accD[i][3] = fmaf(d3, d3, accD[i][3]);
                accV[i][0] = fmaf(an[i], bn.x, accV[i][0]);
                accV[i][1] = fmaf(an[i], bn.y, accV[i][1]);
                accV[i][2] = fmaf(an[i], bn.z, accV[i][2]);
                accV[i][3] = fmaf(an[i], bn.w, accV[i][3]);
            }
        }
        __syncthreads();
    }
    float rp[4] = {0.f, 0.f, 0.f, 0.f};
    float cp[4] = {0.f, 0.f, 0.f, 0.f};
#pragma unroll
    for (int i = 0; i < 4; i++)
#pragma unroll
        for (int j = 0; j < 4; j++) {
            int gi = i0 + ty * 4 + i, gj = j0 + tx * 4 + j;
            float val = (gi == gj) ? accD[i][j] : accD[i][j] * accV[i][j] * (1.0f / 191.0f);
            rp[i] += val; cp[j] += val;
        }
#pragma unroll
    for (int i = 0; i < 4; i++) rred[ty * 4 + i][tx] = rp[i];
#pragma unroll
    for (int j = 0; j < 4; j++) cred[tx * 4 + j][ty] = cp[j];
    __syncthreads();
    if (tid < 64) {
        float s = 0.f;
#pragma unroll
        for (int q = 0; q < 16; q++) s += rred[tid][q];
        atomicAdd(&rowsum[i0 + tid], s);
    } else if (tid < 128) {
        int t = tid - 64;
        float s = 0.f;
#pragma unroll
        for (int q = 0; q < 16; q++) s += cred[t][q];
        atomicAdd(&colsum[j0 + t], s);
    }
    __threadfence();
    __syncthreads();
    if (tid == 0) lastf = (atomicAdd(cnt, 1) == 8);
    __syncthreads();
    if (lastf) {
        __threadfence();
        float v3 = (tid < B_) ? fmaxf(rowsum[tid] + 0.6f, 0.f) : 0.f;
        float v4 = (tid < B_) ? fmaxf(colsum[tid] + 0.6f, 0.f) : 0.f;
        fr[tid] = v3; __syncthreads();
        for (int s = 128; s > 0; s >>= 1) { if (tid < s) fr[tid] += fr[tid + s]; __syncthreads(); }
        float l3 = fr[0] / B_;
        __syncthreads();
        fr[tid] = v4; __syncthreads();
        for (int s = 128; s > 0; s >>= 1) { if (tid < s) fr[tid] += fr[tid + s]; __syncthreads(); }
        float l4 = fr[0] / B_;
        if (tid == 0) {
            out[0] = 0.5f * (acc[0] + acc[1]) / B_;
            out[1] = 0.5f * (l3 + l4);
        }
    }
}

extern "C" void kernel_launch(void* const* d_in, const int* in_sizes, int n_in,
                              void* d_out, int out_size, void* d_ws, size_t ws_size,
                              hipStream_t stream) {
    const float* ev  = (const float*)d_in[0];
    const float* ea  = (const float*)d_in[1];
    const float* Wv  = (const float*)d_in[2];
    const float* Wa1 = (const float*)d_in[3];
    const float* Wa2 = (const float*)d_in[4];
    float* out = (float*)d_out;
    float* ws  = (float*)d_ws;

    size_t off = 0;
    // contiguous zero block: evmean..fa, n2, acc/rowsum/colsum/cnt
    float* evmean  = ws + off; off += B_ * C_;
    float* ind_vec = ws + off; off += B_ * C_;
    float* Hb      = ws + off; off += B_ * C_;
    float* fa      = ws + off; off += B_ * C_;
    float* n2      = ws + off; off += NTOT;
    float* accb    = ws + off;
    float* rowsum  = accb + 16;
    float* colsum  = rowsum + B_;
    int*   cntp    = (int*)(colsum + B_);
    off += 16 + B_ + B_ + 16;
    size_t zero_count = off;
    float* iv_norm = ws + off; off += B_ * C_;
    float* invn    = ws + off; off += NTOT;
    float* SPb     = ws + off; off += B_ * B_;
    float* SNb     = ws + off; off += B_ * B_;
    unsigned char* Abf = (unsigned char*)(ws + off); off += 768 * C_ / 4;   // fp8 bytes

    // per-b: evT fp8 flat (HW_*C_ bytes) + Tb bf16 (B_*HW_ elems)
    size_t perB_f = (size_t)HW_ * C_ / 4 + (size_t)B_ * HW_ / 2;
    size_t avail  = ws_size / 4 > off ? ws_size / 4 - off : 0;
    int chunk = (int)(avail / perB_f);
    chunk &= ~7;                    // multiple of 8 so nb*784 is a multiple of 128
    if (chunk > B_) chunk = B_;
    if (chunk < 8) chunk = 8;
    unsigned char* evT = (unsigned char*)(ws + off);
    unsigned short* Tb = (unsigned short*)(evT + (size_t)chunk * HW_ * C_);

    hipMemsetAsync(ws, 0, zero_count * sizeof(float), stream);

    k_prepA<<<576, 256, 0, stream>>>(Wv, Abf);

    if (chunk >= B_) {
        dim3 gt(13, C_ / 64, B_);
        k_transpose64<<<gt, 256, 0, stream>>>(ev, evT, evmean, 1, 0);
    } else {
        k_evmean<<<B_ * C_ / 4, 256, 0, stream>>>(ev, evmean);
    }

    // audio chain (split-K for occupancy)
    k32<0, 0, 4><<<dim3(8, 3, 4), 256, 0, stream>>>(ea, Wa1, Hb, B_, C_, 2048);
    k32<0, 1, 2><<<dim3(8, 3, 2), 256, 0, stream>>>(Hb, Wa2, fa, B_, C_, C_);

    // visual chain
    k32<0, 0, 2><<<dim3(8, 3, 2), 256, 0, stream>>>(evmean, Wv, ind_vec, B_, C_, C_);
    k_rownorm<<<B_, 64, 0, stream>>>(ind_vec, iv_norm);
    k_Ufp8<<<dim3(8, 3), 256, 0, stream>>>(iv_norm, Wv, Abf);

    if (chunk >= B_) {
        int ntiles = (NTOT / 128) * 6;            // 7056 = 8*882, no pad
        int S = (ntiles + 7) >> 3;
        k_gemm<<<8 * S, 256, 0, stream>>>(Abf, evT, n2, Tb, ntiles);
        k_invn<<<(NTOT + 255) / 256, 256, 0, stream>>>(n2, invn, NTOT);
        dim3 gp(B_ / 4, B_);
        k_pool<<<gp, 256, 0, stream>>>(Tb, invn, SPb, SNb, 0);
    } else {
        for (int b0 = 0; b0 < B_; b0 += chunk) {
            int nb = (B_ - b0 < chunk) ? (B_ - b0) : chunk;
            dim3 gt(13, C_ / 64, nb);
            k_transpose64<<<gt, 256, 0, stream>>>(ev, evT, evmean, 0, b0);
            int ntiles = (nb * HW_ / 128) * 6;
            int S = (ntiles + 7) >> 3;
            k_gemm<<<8 * S, 256, 0, stream>>>(Abf, evT, n2 + (size_t)b0 * HW_, Tb, ntiles);
            int n = nb * HW_;
            k_invn<<<(n + 255) / 256, 256, 0, stream>>>(n2 + (size_t)b0 * HW_,
                                                        invn + (size_t)b0 * HW_, n);
            dim3 gp(B_ / 4, nb);
            k_pool<<<gp, 256, 0, stream>>>(Tb - (size_t)b0 * B_ * HW_, invn, SPb, SNb, b0);
        }
    }

    k_loss12<<<B_, 128, 0, stream>>>(SPb, SNb, accb);
    dim3 gd(B_ / 64, B_ / 64);
    k_distfin<<<gd, 256, 0, stream>>>(ind_vec, iv_norm, fa, accb, rowsum, colsum, cntp, out);
}